// Round 5
// baseline (380.014 us; speedup 1.0000x reference)
//
#include <hip/hip_runtime.h>
#include <hip/hip_bf16.h>

static constexpr int Hd = 768;    // H
static constexpr int H2 = 1536;   // 2H
static constexpr int Cn = 64;     // C (labels)

typedef __attribute__((ext_vector_type(8))) short short8;
typedef __attribute__((ext_vector_type(8))) _Float16 half8;
typedef __attribute__((ext_vector_type(4))) float f32x4;
typedef unsigned short us;

__device__ inline unsigned int f2bf2(float a, float b) {
    __hip_bfloat162 h = __float22bfloat162_rn(float2{a, b});
    return *reinterpret_cast<unsigned int*>(&h);
}

__device__ inline void split1(float x, us& h, us& l) {
    __hip_bfloat16 hb = __float2bfloat16(x);
    float hf = __bfloat162float(hb);
    __hip_bfloat16 lb_ = __float2bfloat16(x - hf);
    h = *reinterpret_cast<us*>(&hb);
    l = *reinterpret_cast<us*>(&lb_);
}

__device__ inline us f2b(float x) {
    __hip_bfloat16 b = __float2bfloat16(x);
    return *reinterpret_cast<us*>(&b);
}

__device__ inline us f2h(float x) {
    _Float16 h = (_Float16)x;
    return *reinterpret_cast<us*>(&h);
}

__device__ inline float b2f(us u) {
    __hip_bfloat16 b = *reinterpret_cast<__hip_bfloat16*>(&u);
    return __bfloat162float(b);
}

// packed fp16 elementwise product: 4x v_pk_mul_f16
__device__ inline short8 hmul8(short8 a, short8 b) {
    half8 x = __builtin_bit_cast(half8, a);
    half8 y = __builtin_bit_cast(half8, b);
    half8 r = x * y;
    return __builtin_bit_cast(short8, r);
}

__device__ inline void gload16(const void* g, void* l) {
    __builtin_amdgcn_global_load_lds(
        (const __attribute__((address_space(1))) unsigned int*)g,
        (__attribute__((address_space(3))) unsigned int*)l, 16, 0, 0);
}

// ---------------- init: widx = -1 ----------------
__global__ void k_init(int* widx, int Wd) {
    int i = blockIdx.x * 256 + threadIdx.x;
    if (i < Wd) widx[i] = -1;
}

__global__ void k_scatter(const int* __restrict__ wmask, int* widx, int L, int Wd) {
    int i = blockIdx.x * 256 + threadIdx.x;
    if (i < L) {
        int m = wmask[i];
        if (m > 0 && m <= Wd) atomicMax(&widx[m - 1], i);  // last token wins
    }
}

// build we directly as hi/lo bf16 split
__global__ void k_build_we_split(const float4* __restrict__ tok, const int* __restrict__ widx,
                                 us* __restrict__ weh, us* __restrict__ wel, int Wd) {
    int i = blockIdx.x * 256 + threadIdx.x;   // over Wd * 192
    if (i >= Wd * 192) return;
    int w = i / 192, c4 = i - w * 192;
    int idx = widx[w];
    float4 v = (idx >= 0) ? tok[idx * 192 + c4] : float4{0.f, 0.f, 0.f, 0.f};
    us hh[4], ll[4];
    split1(v.x, hh[0], ll[0]);
    split1(v.y, hh[1], ll[1]);
    split1(v.z, hh[2], ll[2]);
    split1(v.w, hh[3], ll[3]);
    size_t o = (size_t)w * Hd + c4 * 4;
    *(ushort4*)&weh[o] = ushort4{hh[0], hh[1], hh[2], hh[3]};
    *(ushort4*)&wel[o] = ushort4{ll[0], ll[1], ll[2], ll[3]};
}

// ---------- batched transpose + split: T[n][k]; fmt=0 bf16 hi/lo, fmt=1 fp16 (Th only) ----------
struct TSArgs {
    const float* src[5];
    us* th[5];
    us* tl[5];
    int ld[5];
    int N[5];
    int fmt[5];
};
__global__ __launch_bounds__(256)
void k_tsplit(TSArgs a) {
    __shared__ float tile[64][65];
    const int z = blockIdx.z;
    const int n0 = blockIdx.x * 64, k0 = blockIdx.y * 64;
    if (n0 >= a.N[z]) return;
    const float* W = a.src[z];
    const int ld = a.ld[z];
    for (int idx = threadIdx.x; idx < 4096; idx += 256) {
        int kk = idx >> 6, nn = idx & 63;
        tile[kk][nn] = W[(size_t)(k0 + kk) * ld + n0 + nn];
    }
    __syncthreads();
    us* Th = a.th[z];
    us* Tl = a.tl[z];
    const int fmt = a.fmt[z];
    for (int idx = threadIdx.x; idx < 4096; idx += 256) {
        int nn = idx >> 6, kk = idx & 63;
        size_t o = (size_t)(n0 + nn) * Hd + k0 + kk;
        if (fmt) {
            Th[o] = f2h(tile[kk][nn]);
        } else {
            us h, l;
            split1(tile[kk][nn], h, l);
            Th[o] = h;
            Tl[o] = l;
        }
    }
}

// ---------- row-major hi/lo split ----------
__global__ __launch_bounds__(256)
void k_split(const float* __restrict__ x, int lda, int cols,
             us* __restrict__ h, us* __restrict__ l, int n4) {
    int i = blockIdx.x * 256 + threadIdx.x;
    if (i >= n4) return;
    int c4 = cols >> 2;
    int row = i / c4, cc = (i - row * c4) * 4;
    float4 v = *(const float4*)&x[(size_t)row * lda + cc];
    us hh[4], ll[4];
    split1(v.x, hh[0], ll[0]);
    split1(v.y, hh[1], ll[1]);
    split1(v.z, hh[2], ll[2]);
    split1(v.w, hh[3], ll[3]);
    size_t o = (size_t)row * cols + cc;
    *(ushort4*)&h[o] = ushort4{hh[0], hh[1], hh[2], hh[3]};
    *(ushort4*)&l[o] = ushort4{ll[0], ll[1], ll[2], ll[3]};
}

// ---------- split-bf16 GEMM, LDS double-buffered, K-split partials (small Ms) ----------
__global__ __launch_bounds__(256)
void k_gemm2(const us* __restrict__ Ah, const us* __restrict__ Al,
             const us* __restrict__ BhT, const us* __restrict__ BlT,
             float* __restrict__ Cpart, int M, int N, int K) {
    __shared__ __align__(16) us S[2][4][64 * 32];
    const int tid = threadIdx.x, wave = tid >> 6, lane = tid & 63;
    const int quad = lane >> 4, l15 = lane & 15;
    const int wm = wave & 1, wn = wave >> 1;
    const int m0 = blockIdx.y * 64, n0 = blockIdx.x * 64;
    const int Ks = K / gridDim.z, kbeg = blockIdx.z * Ks, kend = kbeg + Ks;
    float* C = Cpart + (size_t)blockIdx.z * M * N;

    const int srow = wave * 16 + (lane >> 2), soff = (lane & 3) * 8;
    const size_t gaB = (size_t)(m0 + srow) * K + soff;
    const size_t gbB = (size_t)(n0 + srow) * K + soff;
    const int lo = wave * 16 * 32;

    f32x4 acc[2][2];
#pragma unroll
    for (int a = 0; a < 2; ++a)
#pragma unroll
        for (int b = 0; b < 2; ++b) acc[a][b] = (f32x4){0.f, 0.f, 0.f, 0.f};

    auto stage = [&](int p, int k0) {
        gload16(Ah + gaB + k0, &S[p][0][lo]);
        gload16(Al + gaB + k0, &S[p][1][lo]);
        gload16(BhT + gbB + k0, &S[p][2][lo]);
        gload16(BlT + gbB + k0, &S[p][3][lo]);
    };

    int p = 0;
    stage(0, kbeg);
    for (int k0 = kbeg; k0 < kend; k0 += 32) {
        __syncthreads();
        if (k0 + 32 < kend) stage(p ^ 1, k0 + 32);
        short8 ah[2], al[2], bh[2], bl[2];
#pragma unroll
        for (int mt = 0; mt < 2; ++mt) {
            int off = (wm * 32 + mt * 16 + l15) * 32 + quad * 8;
            ah[mt] = *(const short8*)&S[p][0][off];
            al[mt] = *(const short8*)&S[p][1][off];
        }
#pragma unroll
        for (int nt = 0; nt < 2; ++nt) {
            int off = (wn * 32 + nt * 16 + l15) * 32 + quad * 8;
            bh[nt] = *(const short8*)&S[p][2][off];
            bl[nt] = *(const short8*)&S[p][3][off];
        }
#pragma unroll
        for (int mt = 0; mt < 2; ++mt)
#pragma unroll
            for (int nt = 0; nt < 2; ++nt) {
                acc[mt][nt] = __builtin_amdgcn_mfma_f32_16x16x32_bf16(al[mt], bh[nt], acc[mt][nt], 0, 0, 0);
                acc[mt][nt] = __builtin_amdgcn_mfma_f32_16x16x32_bf16(ah[mt], bl[nt], acc[mt][nt], 0, 0, 0);
                acc[mt][nt] = __builtin_amdgcn_mfma_f32_16x16x32_bf16(ah[mt], bh[nt], acc[mt][nt], 0, 0, 0);
            }
        p ^= 1;
    }
#pragma unroll
    for (int mt = 0; mt < 2; ++mt)
#pragma unroll
        for (int nt = 0; nt < 2; ++nt) {
            int col = n0 + wn * 32 + nt * 16 + l15;
#pragma unroll
            for (int reg = 0; reg < 4; ++reg) {
                int row = m0 + wm * 32 + mt * 16 + quad * 4 + reg;
                C[(size_t)row * N + col] = acc[mt][nt][reg];
            }
        }
}

// ---------- split-bf16 GEMM, z=1, fused outputs (bias + f32 / hi-lo split / 16-bit) ----------
__global__ __launch_bounds__(256)
void k_gemm3(const us* __restrict__ Ah, const us* __restrict__ Al,
             const us* __restrict__ BhT, const us* __restrict__ BlT,
             const float* __restrict__ bias, float* __restrict__ outF,
             us* __restrict__ sh, us* __restrict__ sl, us* __restrict__ bh16,
             int fp16out, int scols, int N, int K) {
    __shared__ __align__(16) us S[2][4][64 * 32];
    const int tid = threadIdx.x, wave = tid >> 6, lane = tid & 63;
    const int quad = lane >> 4, l15 = lane & 15;
    const int wm = wave & 1, wn = wave >> 1;
    const int m0 = blockIdx.y * 64, n0 = blockIdx.x * 64;

    const int srow = wave * 16 + (lane >> 2), soff = (lane & 3) * 8;
    const size_t gaB = (size_t)(m0 + srow) * K + soff;
    const size_t gbB = (size_t)(n0 + srow) * K + soff;
    const int lo = wave * 16 * 32;

    f32x4 acc[2][2];
#pragma unroll
    for (int a = 0; a < 2; ++a)
#pragma unroll
        for (int b = 0; b < 2; ++b) acc[a][b] = (f32x4){0.f, 0.f, 0.f, 0.f};

    auto stage = [&](int p, int k0) {
        gload16(Ah + gaB + k0, &S[p][0][lo]);
        gload16(Al + gaB + k0, &S[p][1][lo]);
        gload16(BhT + gbB + k0, &S[p][2][lo]);
        gload16(BlT + gbB + k0, &S[p][3][lo]);
    };

    int p = 0;
    stage(0, 0);
    for (int k0 = 0; k0 < K; k0 += 32) {
        __syncthreads();
        if (k0 + 32 < K) stage(p ^ 1, k0 + 32);
        short8 ah[2], al[2], bh[2], bl[2];
#pragma unroll
        for (int mt = 0; mt < 2; ++mt) {
            int off = (wm * 32 + mt * 16 + l15) * 32 + quad * 8;
            ah[mt] = *(const short8*)&S[p][0][off];
            al[mt] = *(const short8*)&S[p][1][off];
        }
#pragma unroll
        for (int nt = 0; nt < 2; ++nt) {
            int off = (wn * 32 + nt * 16 + l15) * 32 + quad * 8;
            bh[nt] = *(const short8*)&S[p][2][off];
            bl[nt] = *(const short8*)&S[p][3][off];
        }
#pragma unroll
        for (int mt = 0; mt < 2; ++mt)
#pragma unroll
            for (int nt = 0; nt < 2; ++nt) {
                acc[mt][nt] = __builtin_amdgcn_mfma_f32_16x16x32_bf16(al[mt], bh[nt], acc[mt][nt], 0, 0, 0);
                acc[mt][nt] = __builtin_amdgcn_mfma_f32_16x16x32_bf16(ah[mt], bl[nt], acc[mt][nt], 0, 0, 0);
                acc[mt][nt] = __builtin_amdgcn_mfma_f32_16x16x32_bf16(ah[mt], bh[nt], acc[mt][nt], 0, 0, 0);
            }
        p ^= 1;
    }
#pragma unroll
    for (int mt = 0; mt < 2; ++mt)
#pragma unroll
        for (int nt = 0; nt < 2; ++nt) {
            int col = n0 + wn * 32 + nt * 16 + l15;
            float bb = bias ? bias[col] : 0.f;
#pragma unroll
            for (int reg = 0; reg < 4; ++reg) {
                int row = m0 + wm * 32 + mt * 16 + quad * 4 + reg;
                float v = acc[mt][nt][reg] + bb;
                if (outF) outF[(size_t)row * N + col] = v;
                if (sh) {
                    if (col < scols) {
                        us h, l;
                        split1(v, h, l);
                        size_t o = (size_t)row * scols + col;
                        sh[o] = h;
                        sl[o] = l;
                    } else if (bh16) {
                        bh16[(size_t)row * scols + (col - scols)] = fp16out ? f2h(v) : f2b(v);
                    }
                }
            }
        }
}

// ---------- reduce partials + bias; f32 out + hi/lo split (col<scols) + 16-bit (col>=scols) ----------
__global__ __launch_bounds__(256)
void k_reduce(const float* __restrict__ part, int S, int MN, int N,
              const float* __restrict__ bias, float* __restrict__ outF,
              us* __restrict__ sh, us* __restrict__ sl, int scols,
              us* __restrict__ bh16, int fp16out) {
    int i = blockIdx.x * 256 + threadIdx.x;
    if (i >= MN) return;
    float v = 0.f;
    for (int s = 0; s < S; ++s) v += part[(size_t)s * MN + i];
    int row = i / N, col = i - row * N;
    if (bias) v += bias[col];
    if (outF) outF[i] = v;
    if (col < scols) {
        if (sh) {
            us h, l;
            split1(v, h, l);
            size_t o = (size_t)row * scols + col;
            sh[o] = h;
            sl[o] = l;
        }
    } else if (bh16) {
        bh16[(size_t)row * scols + (col - scols)] = fp16out ? f2h(v) : f2b(v);
    }
}

// ---------------- P-GEMM v12: barrier-free K-loop — per-wave private LDS slices ----------------
// R4 post-mortem: occupancy reshape regressed (v11) and all schedule variants at 2/SIMD
// plateau ~118us with ~1200 cyc/step of stall unexplained by pipe demand. Last remaining
// structural suspect: the block-wide s_barrier every k-step (4 waves across 4 SIMDs must
// converge 24x, with 2 independent blocks/CU injecting skew).
// v12: each wave stages a PRIVATE LDS slice (its 64 A-rows + 64 B-rows; duplicated across
// the 2 waves sharing a half -> 2x L2 reads, all L2-hits). K-loop has ZERO barriers:
// per-wave vmcnt(0) waits only own gloads (issued a full step earlier), reg-dbuf frags
// (v10), counted lgkmcnt(10) before re-staging a buffer (older DS reads retired in-order
// — same counted-lgkm idiom as the 8-phase template). 2 bufs x 8KB x 4 waves = 64KB.
__global__ __launch_bounds__(256, 2)
void k_mfma12(const us* __restrict__ t1b,   // (1024,768) fp16
              const us* __restrict__ W1ct,  // (768,768) fp16 [j][k]
              const us* __restrict__ lb1b,  // (64,768) fp16
              const float* __restrict__ Aw, // (1024,768) f32
              const float* __restrict__ Bc, // (64,768) f32 (includes b1)
              const float* __restrict__ W2, // (768,3) f32
              float* __restrict__ scr) {    // (6,1024,64,3) f32 partials
    __shared__ __align__(16) us As[4][2][2048];  // [wave][buf][q=4][row=64][8], 4KB/buf
    __shared__ __align__(16) us Bs[4][2][2048];
    __shared__ __align__(16) us lbs[2][Hd];      // lb1 rows for the 2 labels
    __shared__ float sred[2 * 128 * 3];

    const int tid = threadIdx.x, wave = tid >> 6, lane = tid & 63;
    const int quad = lane >> 4, l15 = lane & 15;
    const int wm = wave & 1, wn = wave >> 1;

    // L2-locality decode: b = xcd + 8*(jx*32 + cp); my = xcd
    const int b = blockIdx.x;
    const int xcd = b & 7, slot = b >> 3;    // slot 0..191
    const int jx = slot >> 5;                // 0..5
    const int cp = slot & 31;                // 0..31 (varies fastest)
    const int c0 = cp * 2;
    const int jt = jx * 128, m0 = xcd * 128;

    for (int i = tid; i < 2 * 128 * 3; i += 256) sred[i] = 0.f;
    if (tid < 192) {                          // stage lb1 rows c0,c0+1 (3 KB)
        int cc = tid / 96, o = (tid - cc * 96) * 8;
        *(short8*)&lbs[cc][o] = *(const short8*)&lb1b[(size_t)(c0 + cc) * Hd + o];
    }

    // per-wave private staging: wave's A slice = rows [wm*64, wm*64+64), B = [wn*64, +64)
    const us* gA = W1ct + (size_t)(jt + wm * 64 + lane) * Hd;
    const us* gB = t1b + (size_t)(m0 + wn * 64 + lane) * Hd;

    f32x4 acc0[4][4], acc1[4][4];
#pragma unroll
    for (int mt = 0; mt < 4; ++mt)
#pragma unroll
        for (int nt = 0; nt < 4; ++nt) {
            acc0[mt][nt] = (f32x4){0.f, 0.f, 0.f, 0.f};
            acc1[mt][nt] = (f32x4){0.f, 0.f, 0.f, 0.f};
        }

    // stage one 32-k step into private buf p: 4 A-chunks + 4 B-chunks of 1KB
    auto stage = [&](int p, int k0) {
#pragma unroll
        for (int q = 0; q < 4; ++q) {
            gload16(gA + k0 + q * 8, &As[wave][p][q * 512]);
            gload16(gB + k0 + q * 8, &Bs[wave][p][q * 512]);
        }
    };

    // fragment read bases within the wave's slice: elem (q,row) at us-idx q*512 + row*8
    const int rb = quad * 512 + l15 * 8;

    auto readFrags = [&](short8 (&af)[4], short8 (&bf)[4], short8& l0, short8& l1,
                         int buf, int k0) {
        const us* Ab = &As[wave][buf][0];
        const us* Bb = &Bs[wave][buf][0];
#pragma unroll
        for (int mt = 0; mt < 4; ++mt) af[mt] = *(const short8*)&Ab[rb + mt * 128];
#pragma unroll
        for (int nt = 0; nt < 4; ++nt) bf[nt] = *(const short8*)&Bb[rb + nt * 128];
        l0 = *(const short8*)&lbs[0][k0 + quad * 8];
        l1 = *(const short8*)&lbs[1][k0 + quad * 8];
    };

    auto cluster = [&](const short8 (&af)[4], const short8 (&bf)[4],
                       const short8& l0, const short8& l1) {
        __builtin_amdgcn_s_setprio(1);
#pragma unroll
        for (int mt = 0; mt < 4; ++mt) {
            short8 a0 = hmul8(af[mt], l0);
            short8 a1 = hmul8(af[mt], l1);
#pragma unroll
            for (int nt = 0; nt < 4; ++nt) {
                acc0[mt][nt] = __builtin_amdgcn_mfma_f32_16x16x32_f16(
                    __builtin_bit_cast(half8, a0),
                    __builtin_bit_cast(half8, bf[nt]), acc0[mt][nt], 0, 0, 0);
                acc1[mt][nt] = __builtin_amdgcn_mfma_f32_16x16x32_f16(
                    __builtin_bit_cast(half8, a1),
                    __builtin_bit_cast(half8, bf[nt]), acc1[mt][nt], 0, 0, 0);
            }
        }
        __builtin_amdgcn_s_setprio(0);
    };

    __syncthreads();        // lbs/sred visible to all waves (the only pre-epilogue barrier)

    stage(0, 0);            // 8 gloads
    stage(1, 32);           // 8 more (16 in flight)
    asm volatile("s_waitcnt vmcnt(8)" ::: "memory");   // buf0 staged
    short8 afC[4], bfC[4], lvC0, lvC1;   // current regs
    short8 afN[4], bfN[4], lvN0, lvN1;   // next regs
    readFrags(afC, bfC, lvC0, lvC1, 0, 0);

    // 24 k-steps; buf parity: step s lives in buf s&1
    for (int i = 0; i < 24; i += 2) {
        // ---- step i: compute C (k=32i); read N (k+32); restage buf i&1 for k+64 ----
        if (i + 1 < 24) {
            asm volatile("s_waitcnt vmcnt(0)" ::: "memory");   // own stage for step i+1 done
            readFrags(afN, bfN, lvN0, lvN1, (i + 1) & 1, (i + 1) * 32);
            __builtin_amdgcn_sched_barrier(0);
            asm volatile("s_waitcnt lgkmcnt(10)" ::: "memory"); // C's reads retired (in-order DS)
            if (i + 2 < 24) stage(i & 1, (i + 2) * 32);
            __builtin_amdgcn_sched_barrier(0);
        }
        cluster(afC, bfC, lvC0, lvC1);
        // ---- step i+1: compute N; read C (k+64); restage buf (i+1)&1 for k+96 ----
        if (i + 2 < 24) {
            asm volatile("s_waitcnt vmcnt(0)" ::: "memory");
            readFrags(afC, bfC, lvC0, lvC1, (i + 2) & 1, (i + 2) * 32);
            __builtin_amdgcn_sched_barrier(0);
            asm volatile("s_waitcnt lgkmcnt(10)" ::: "memory");
            if (i + 3 < 24) stage((i + 1) & 1, (i + 3) * 32);
            __builtin_amdgcn_sched_barrier(0);
        }
        cluster(afN, bfN, lvN0, lvN1);
    }

    // ---- epilogue: per c: h = relu(P + Aw + Bc); sacc[w][r] += h*W2[j][r] ----
    // j = jt + wm*64 + mt*16 + quad*4 + reg ; w = m0 + wn*64 + nt*16 + l15
    float bcv0[4][4], bcv1[4][4], w2v[4][4][3];
#pragma unroll
    for (int mt = 0; mt < 4; ++mt) {
        const int jb = jt + wm * 64 + mt * 16 + quad * 4;
        float4 b4 = *(const float4*)&Bc[(size_t)c0 * Hd + jb];
        bcv0[mt][0] = b4.x; bcv0[mt][1] = b4.y; bcv0[mt][2] = b4.z; bcv0[mt][3] = b4.w;
        float4 b5 = *(const float4*)&Bc[(size_t)(c0 + 1) * Hd + jb];
        bcv1[mt][0] = b5.x; bcv1[mt][1] = b5.y; bcv1[mt][2] = b5.z; bcv1[mt][3] = b5.w;
#pragma unroll
        for (int reg = 0; reg < 4; ++reg)
#pragma unroll
            for (int r = 0; r < 3; ++r) w2v[mt][reg][r] = W2[(jb + reg) * 3 + r];
    }

    auto reduce_c = [&](const f32x4 (&ac)[4][4], const float (&bcv)[4][4], int cc) {
#pragma unroll
        for (int nt = 0; nt < 4; ++nt) {
            const int w = m0 + wn * 64 + nt * 16 + l15;
            const float* awp = Aw + (size_t)w * Hd + jt + wm * 64;
            float s0 = 0.f, s1 = 0.f, s2 = 0.f;
#pragma unroll
            for (int mt = 0; mt < 4; ++mt) {
                float4 a4 = *(const float4*)&awp[mt * 16 + quad * 4];
                float av[4] = {a4.x, a4.y, a4.z, a4.w};
#pragma unroll
                for (int reg = 0; reg < 4; ++reg) {
                    float h = ac[mt][nt][reg] + av[reg] + bcv[mt][reg];
                    h = h > 0.f ? h : 0.f;
                    s0 += h * w2v[mt][reg][0];
                    s1 += h * w2v[mt][reg][1];
                    s2 += h * w2v[mt][reg][2];
                }
            }
            s0 += __shfl_xor(s0, 16); s0 += __shfl_xor(s0, 32);
            s1 += __shfl_xor(s1, 16); s1 += __shfl_xor(s1, 32);
            s2 += __shfl_xor(s2, 16); s2 += __shfl_xor(s2, 32);
            if (quad == 0) {
                const int wl = wn * 64 + nt * 16 + l15;
                atomicAdd(&sred[cc * 384 + wl * 3 + 0], s0);   // LDS, 2-way (wm)
                atomicAdd(&sred[cc * 384 + wl * 3 + 1], s1);
                atomicAdd(&sred[cc * 384 + wl * 3 + 2], s2);
            }
        }
    };
    reduce_c(acc0, bcv0, 0);
    reduce_c(acc1, bcv1, 1);
    __syncthreads();

    // non-atomic store to per-jx scratch slot (disjoint across blocks)
    float* slab = scr + ((size_t)jx * 1024 * Cn + (size_t)m0 * Cn) * 3;
    for (int i = tid; i < 2 * 128 * 3; i += 256) {
        int cc = i / 384, j = i - cc * 384;
        int wl = j / 3, r = j - wl * 3;
        slab[((size_t)wl * Cn + (c0 + cc)) * 3 + r] = sred[i];
    }
}

// ---------- final: out = b2 + sum_jx scr[jx] ----------
__global__ __launch_bounds__(256)
void k_scores(const float* __restrict__ scr, const float* __restrict__ b2,
              float* __restrict__ out, int n) {
    int i = blockIdx.x * 256 + threadIdx.x;
    if (i >= n) return;
    float v = b2[i % 3];
#pragma unroll
    for (int s = 0; s < 6; ++s) v += scr[(size_t)s * n + i];
    out[i] = v;
}

extern "C" void kernel_launch(void* const* d_in, const int* in_sizes, int n_in,
                              void* d_out, int out_size, void* d_ws, size_t ws_size,
                              hipStream_t stream) {
    const float* tok    = (const float*)d_in[0];
    const int*   wmask  = (const int*)d_in[1];
    const float* labe   = (const float*)d_in[3];
    const float* W_tok  = (const float*)d_in[4];
    const float* b_tok  = (const float*)d_in[5];
    const float* W_lab  = (const float*)d_in[6];
    const float* b_lab  = (const float*)d_in[7];
    const float* W1     = (const float*)d_in[8];
    const float* b1     = (const float*)d_in[9];
    const float* W2     = (const float*)d_in[10];
    const float* b2     = (const float*)d_in[11];
    float* out = (float*)d_out;

    const int L  = in_sizes[1];
    const int Wd = out_size / (Cn * 3);   // 1024

    char* ws = (char*)d_ws;
    size_t off = 0;
    auto alloc = [&](size_t bytes) { char* p = ws + off; off += (bytes + 255) & ~(size_t)255; return p; };
    // ---- persistent region ----
    int*   widx  = (int*)alloc(4096);
    float* Abuf  = (float*)alloc((size_t)Wd * Hd * 4);
    float* Bbuf  = (float*)alloc((size_t)Cn * Hd * 4);
    us* W1ct  = (us*)alloc((size_t)Hd * Hd * 2);   // fp16
    us* W1cl  = (us*)alloc((size_t)Hd * Hd * 2);   // unused
    us* t1b   = (us*)alloc((size_t)Wd * Hd * 2);   // fp16
    us* lb1b  = (us*)alloc((size_t)Cn * Hd * 2);   // fp16
    float* scr = (float*)alloc((size_t)6 * Wd * Cn * 3 * 4);   // 4.72 MB partials
    // ---- scratch region ----
    us* WtTh  = (us*)alloc((size_t)H2 * Hd * 2);
    us* WtTl  = (us*)alloc((size_t)H2 * Hd * 2);
    us* WlTh  = (us*)alloc((size_t)H2 * Hd * 2);
    us* WlTl  = (us*)alloc((size_t)H2 * Hd * 2);
    us* W1aTh = (us*)alloc((size_t)Hd * Hd * 2);
    us* W1aTl = (us*)alloc((size_t)Hd * Hd * 2);
    us* W1bTh = (us*)alloc((size_t)Hd * Hd * 2);
    us* W1bTl = (us*)alloc((size_t)Hd * Hd * 2);
    us* weh   = (us*)alloc((size_t)Wd * Hd * 2);
    us* wel   = (us*)alloc((size_t)Wd * Hd * 2);
    us* lah   = (us*)alloc((size_t)Cn * Hd * 2);
    us* lal   = (us*)alloc((size_t)Cn * Hd * 2);
    us* t0h   = (us*)alloc((size_t)Wd * Hd * 2);
    us* t0l   = (us*)alloc((size_t)Wd * Hd * 2);
    us* lb0h  = (us*)alloc((size_t)Cn * Hd * 2);
    us* lb0l  = (us*)alloc((size_t)Cn * Hd * 2);
    float* part = (float*)alloc((size_t)8 * Cn * H2 * 4);

    // 1) init + scatter + we split
    k_init<<<(Wd + 255) / 256, 256, 0, stream>>>(widx, Wd);
    k_scatter<<<(L + 255) / 256, 256, 0, stream>>>(wmask, widx, L, Wd);
    k_build_we_split<<<(Wd * 192 + 255) / 256, 256, 0, stream>>>((const float4*)tok, widx, weh, wel, Wd);

    // 2) batched weight transpose+split (W1c -> fp16)
    TSArgs ts;
    ts.src[0] = W_tok;  ts.th[0] = WtTh;  ts.tl[0] = WtTl;  ts.ld[0] = H2; ts.N[0] = H2; ts.fmt[0] = 0;
    ts.src[1] = W_lab;  ts.th[1] = WlTh;  ts.tl[1] = WlTl;  ts.ld[1] = H2; ts.N[1] = H2; ts.fmt[1] = 0;
    ts.src[2] = W1;                         ts.th[2] = W1aTh; ts.tl[2] = W1aTl; ts.ld[2] = Hd; ts.N[2] = Hd; ts.fmt[2] = 0;
    ts.src[3] = W1 + (size_t)Hd * Hd;       ts.th[3] = W1bTh; ts.tl[3] = W1bTl; ts.ld[3] = Hd; ts.N[3] = Hd; ts.fmt[3] = 0;
    ts.src[4] = W1 + (size_t)2 * Hd * Hd;   ts.th[4] = W1ct;  ts.tl[4] = W1cl;  ts.ld[4] = Hd; ts.N[4] = Hd; ts.fmt[4] = 1;
    k_tsplit<<<dim3(H2 / 64, Hd / 64, 5), 256, 0, stream>>>(ts);

    // 3) label emb split
    k_split<<<(Cn * Hd / 4 + 255) / 256, 256, 0, stream>>>(labe, Hd, Hd, lah, lal, Cn * Hd / 4);

    // 4) t = we @ W_tok + b_tok -> fused t0 hi/lo + t1b fp16
    k_gemm3<<<dim3(H2 / 64, Wd / 64), 256, 0, stream>>>(weh, wel, WtTh, WtTl, b_tok,
                                                        nullptr, t0h, t0l, t1b, 1, Hd, H2, Hd);

    // 5) lb = labe @ W_lab + b_lab (64x1536), z=8 -> reduce (lb0 split + lb1b fp16)
    k_gemm2<<<dim3(H2 / 64, 1, 8), 256, 0, stream>>>(lah, lal, WlTh, WlTl, part, Cn, H2, Hd);
    k_reduce<<<(Cn * H2 + 255) / 256, 256, 0, stream>>>(part, 8, Cn * H2, H2, b_lab, nullptr, lb0h, lb0l, Hd, lb1b, 1);

    // 6) Aw = t0 @ W1a (1024x768) -> fused f32 write
    k_gemm3<<<dim3(Hd / 64, Wd / 64), 256, 0, stream>>>(t0h, t0l, W1aTh, W1aTl, nullptr,
                                                        Abuf, nullptr, nullptr, nullptr, 0, 0, Hd, Hd);

    // 7) Bc = lb0 @ W1b + b1 (64x768), z=8 -> reduce
    k_gemm2<<<dim3(Hd / 64, 1, 8), 256, 0, stream>>>(lb0h, lb0l, W1bTh, W1bTl, part, Cn, Hd, Hd);
    k_reduce<<<(Cn * Hd + 255) / 256, 256, 0, stream>>>(part, 8, Cn * Hd, Hd, b1, Bbuf, nullptr, nullptr, Hd, nullptr, 0);

    // 8) fused fp16 P-GEMM v12 (barrier-free, per-wave private slices) -> scratch
    k_mfma12<<<1536, 256, 0, stream>>>(t1b, W1ct, lb1b, Abuf, Bbuf, W2, scr);

    // 9) out = b2 + sum_jx scr
    k_scores<<<(Wd * Cn * 3 + 255) / 256, 256, 0, stream>>>(scr, b2, out, Wd * Cn * 3);
}

// Round 6
// 308.789 us; speedup vs baseline: 1.2307x; 1.2307x over previous
//
#include <hip/hip_runtime.h>
#include <hip/hip_bf16.h>

static constexpr int Hd = 768;    // H
static constexpr int H2 = 1536;   // 2H
static constexpr int Cn = 64;     // C (labels)

typedef __attribute__((ext_vector_type(8))) short short8;
typedef __attribute__((ext_vector_type(8))) _Float16 half8;
typedef __attribute__((ext_vector_type(4))) float f32x4;
typedef unsigned short us;

__device__ inline void split1(float x, us& h, us& l) {
    __hip_bfloat16 hb = __float2bfloat16(x);
    float hf = __bfloat162float(hb);
    __hip_bfloat16 lb_ = __float2bfloat16(x - hf);
    h = *reinterpret_cast<us*>(&hb);
    l = *reinterpret_cast<us*>(&lb_);
}

__device__ inline us f2b(float x) {
    __hip_bfloat16 b = __float2bfloat16(x);
    return *reinterpret_cast<us*>(&b);
}

__device__ inline us f2h(float x) {
    _Float16 h = (_Float16)x;
    return *reinterpret_cast<us*>(&h);
}

// packed fp16 elementwise product: 4x v_pk_mul_f16
__device__ inline short8 hmul8(short8 a, short8 b) {
    half8 x = __builtin_bit_cast(half8, a);
    half8 y = __builtin_bit_cast(half8, b);
    half8 r = x * y;
    return __builtin_bit_cast(short8, r);
}

__device__ inline void gload16(const void* g, void* l) {
    __builtin_amdgcn_global_load_lds(
        (const __attribute__((address_space(1))) unsigned int*)g,
        (__attribute__((address_space(3))) unsigned int*)l, 16, 0, 0);
}

// ---------------- init: widx = -1 ----------------
__global__ void k_init(int* widx, int Wd) {
    int i = blockIdx.x * 256 + threadIdx.x;
    if (i < Wd) widx[i] = -1;
}

__global__ void k_scatter(const int* __restrict__ wmask, int* widx, int L, int Wd) {
    int i = blockIdx.x * 256 + threadIdx.x;
    if (i < L) {
        int m = wmask[i];
        if (m > 0 && m <= Wd) atomicMax(&widx[m - 1], i);  // last token wins
    }
}

// build we directly as hi/lo bf16 split
__global__ void k_build_we_split(const float4* __restrict__ tok, const int* __restrict__ widx,
                                 us* __restrict__ weh, us* __restrict__ wel, int Wd) {
    int i = blockIdx.x * 256 + threadIdx.x;   // over Wd * 192
    if (i >= Wd * 192) return;
    int w = i / 192, c4 = i - w * 192;
    int idx = widx[w];
    float4 v = (idx >= 0) ? tok[idx * 192 + c4] : float4{0.f, 0.f, 0.f, 0.f};
    us hh[4], ll[4];
    split1(v.x, hh[0], ll[0]);
    split1(v.y, hh[1], ll[1]);
    split1(v.z, hh[2], ll[2]);
    split1(v.w, hh[3], ll[3]);
    size_t o = (size_t)w * Hd + c4 * 4;
    *(ushort4*)&weh[o] = ushort4{hh[0], hh[1], hh[2], hh[3]};
    *(ushort4*)&wel[o] = ushort4{ll[0], ll[1], ll[2], ll[3]};
}

// ---------- batched transpose + split: T[n][k]; fmt=0 bf16 hi/lo, fmt=1 fp16 (Th only) ----------
struct TSArgs {
    const float* src[5];
    us* th[5];
    us* tl[5];
    int ld[5];
    int N[5];
    int fmt[5];
};
__global__ __launch_bounds__(256)
void k_tsplit(TSArgs a) {
    __shared__ float tile[64][65];
    const int z = blockIdx.z;
    const int n0 = blockIdx.x * 64, k0 = blockIdx.y * 64;
    if (n0 >= a.N[z]) return;
    const float* W = a.src[z];
    const int ld = a.ld[z];
    for (int idx = threadIdx.x; idx < 4096; idx += 256) {
        int kk = idx >> 6, nn = idx & 63;
        tile[kk][nn] = W[(size_t)(k0 + kk) * ld + n0 + nn];
    }
    __syncthreads();
    us* Th = a.th[z];
    us* Tl = a.tl[z];
    const int fmt = a.fmt[z];
    for (int idx = threadIdx.x; idx < 4096; idx += 256) {
        int nn = idx >> 6, kk = idx & 63;
        size_t o = (size_t)(n0 + nn) * Hd + k0 + kk;
        if (fmt) {
            Th[o] = f2h(tile[kk][nn]);
        } else {
            us h, l;
            split1(tile[kk][nn], h, l);
            Th[o] = h;
            Tl[o] = l;
        }
    }
}

// ---------- row-major hi/lo split ----------
__global__ __launch_bounds__(256)
void k_split(const float* __restrict__ x, int lda, int cols,
             us* __restrict__ h, us* __restrict__ l, int n4) {
    int i = blockIdx.x * 256 + threadIdx.x;
    if (i >= n4) return;
    int c4 = cols >> 2;
    int row = i / c4, cc = (i - row * c4) * 4;
    float4 v = *(const float4*)&x[(size_t)row * lda + cc];
    us hh[4], ll[4];
    split1(v.x, hh[0], ll[0]);
    split1(v.y, hh[1], ll[1]);
    split1(v.z, hh[2], ll[2]);
    split1(v.w, hh[3], ll[3]);
    size_t o = (size_t)row * cols + cc;
    *(ushort4*)&h[o] = ushort4{hh[0], hh[1], hh[2], hh[3]};
    *(ushort4*)&l[o] = ushort4{ll[0], ll[1], ll[2], ll[3]};
}

// ---------- split-bf16 GEMM, LDS double-buffered, K-split partials (small Ms) ----------
__global__ __launch_bounds__(256)
void k_gemm2(const us* __restrict__ Ah, const us* __restrict__ Al,
             const us* __restrict__ BhT, const us* __restrict__ BlT,
             float* __restrict__ Cpart, int M, int N, int K) {
    __shared__ __align__(16) us S[2][4][64 * 32];
    const int tid = threadIdx.x, wave = tid >> 6, lane = tid & 63;
    const int quad = lane >> 4, l15 = lane & 15;
    const int wm = wave & 1, wn = wave >> 1;
    const int m0 = blockIdx.y * 64, n0 = blockIdx.x * 64;
    const int Ks = K / gridDim.z, kbeg = blockIdx.z * Ks, kend = kbeg + Ks;
    float* C = Cpart + (size_t)blockIdx.z * M * N;

    const int srow = wave * 16 + (lane >> 2), soff = (lane & 3) * 8;
    const size_t gaB = (size_t)(m0 + srow) * K + soff;
    const size_t gbB = (size_t)(n0 + srow) * K + soff;
    const int lo = wave * 16 * 32;

    f32x4 acc[2][2];
#pragma unroll
    for (int a = 0; a < 2; ++a)
#pragma unroll
        for (int b = 0; b < 2; ++b) acc[a][b] = (f32x4){0.f, 0.f, 0.f, 0.f};

    auto stage = [&](int p, int k0) {
        gload16(Ah + gaB + k0, &S[p][0][lo]);
        gload16(Al + gaB + k0, &S[p][1][lo]);
        gload16(BhT + gbB + k0, &S[p][2][lo]);
        gload16(BlT + gbB + k0, &S[p][3][lo]);
    };

    int p = 0;
    stage(0, kbeg);
    for (int k0 = kbeg; k0 < kend; k0 += 32) {
        __syncthreads();
        if (k0 + 32 < kend) stage(p ^ 1, k0 + 32);
        short8 ah[2], al[2], bh[2], bl[2];
#pragma unroll
        for (int mt = 0; mt < 2; ++mt) {
            int off = (wm * 32 + mt * 16 + l15) * 32 + quad * 8;
            ah[mt] = *(const short8*)&S[p][0][off];
            al[mt] = *(const short8*)&S[p][1][off];
        }
#pragma unroll
        for (int nt = 0; nt < 2; ++nt) {
            int off = (wn * 32 + nt * 16 + l15) * 32 + quad * 8;
            bh[nt] = *(const short8*)&S[p][2][off];
            bl[nt] = *(const short8*)&S[p][3][off];
        }
#pragma unroll
        for (int mt = 0; mt < 2; ++mt)
#pragma unroll
            for (int nt = 0; nt < 2; ++nt) {
                acc[mt][nt] = __builtin_amdgcn_mfma_f32_16x16x32_bf16(al[mt], bh[nt], acc[mt][nt], 0, 0, 0);
                acc[mt][nt] = __builtin_amdgcn_mfma_f32_16x16x32_bf16(ah[mt], bl[nt], acc[mt][nt], 0, 0, 0);
                acc[mt][nt] = __builtin_amdgcn_mfma_f32_16x16x32_bf16(ah[mt], bh[nt], acc[mt][nt], 0, 0, 0);
            }
        p ^= 1;
    }
#pragma unroll
    for (int mt = 0; mt < 2; ++mt)
#pragma unroll
        for (int nt = 0; nt < 2; ++nt) {
            int col = n0 + wn * 32 + nt * 16 + l15;
#pragma unroll
            for (int reg = 0; reg < 4; ++reg) {
                int row = m0 + wm * 32 + mt * 16 + quad * 4 + reg;
                C[(size_t)row * N + col] = acc[mt][nt][reg];
            }
        }
}

// ---------- split-bf16 GEMM, z=1, fused outputs (bias + f32 / hi-lo split / 16-bit) ----------
__global__ __launch_bounds__(256)
void k_gemm3(const us* __restrict__ Ah, const us* __restrict__ Al,
             const us* __restrict__ BhT, const us* __restrict__ BlT,
             const float* __restrict__ bias, float* __restrict__ outF,
             us* __restrict__ sh, us* __restrict__ sl, us* __restrict__ bh16,
             int fp16out, int scols, int N, int K) {
    __shared__ __align__(16) us S[2][4][64 * 32];
    const int tid = threadIdx.x, wave = tid >> 6, lane = tid & 63;
    const int quad = lane >> 4, l15 = lane & 15;
    const int wm = wave & 1, wn = wave >> 1;
    const int m0 = blockIdx.y * 64, n0 = blockIdx.x * 64;

    const int srow = wave * 16 + (lane >> 2), soff = (lane & 3) * 8;
    const size_t gaB = (size_t)(m0 + srow) * K + soff;
    const size_t gbB = (size_t)(n0 + srow) * K + soff;
    const int lo = wave * 16 * 32;

    f32x4 acc[2][2];
#pragma unroll
    for (int a = 0; a < 2; ++a)
#pragma unroll
        for (int b = 0; b < 2; ++b) acc[a][b] = (f32x4){0.f, 0.f, 0.f, 0.f};

    auto stage = [&](int p, int k0) {
        gload16(Ah + gaB + k0, &S[p][0][lo]);
        gload16(Al + gaB + k0, &S[p][1][lo]);
        gload16(BhT + gbB + k0, &S[p][2][lo]);
        gload16(BlT + gbB + k0, &S[p][3][lo]);
    };

    int p = 0;
    stage(0, 0);
    for (int k0 = 0; k0 < K; k0 += 32) {
        __syncthreads();
        if (k0 + 32 < K) stage(p ^ 1, k0 + 32);
        short8 ah[2], al[2], bh[2], bl[2];
#pragma unroll
        for (int mt = 0; mt < 2; ++mt) {
            int off = (wm * 32 + mt * 16 + l15) * 32 + quad * 8;
            ah[mt] = *(const short8*)&S[p][0][off];
            al[mt] = *(const short8*)&S[p][1][off];
        }
#pragma unroll
        for (int nt = 0; nt < 2; ++nt) {
            int off = (wn * 32 + nt * 16 + l15) * 32 + quad * 8;
            bh[nt] = *(const short8*)&S[p][2][off];
            bl[nt] = *(const short8*)&S[p][3][off];
        }
#pragma unroll
        for (int mt = 0; mt < 2; ++mt)
#pragma unroll
            for (int nt = 0; nt < 2; ++nt) {
                acc[mt][nt] = __builtin_amdgcn_mfma_f32_16x16x32_bf16(al[mt], bh[nt], acc[mt][nt], 0, 0, 0);
                acc[mt][nt] = __builtin_amdgcn_mfma_f32_16x16x32_bf16(ah[mt], bl[nt], acc[mt][nt], 0, 0, 0);
                acc[mt][nt] = __builtin_amdgcn_mfma_f32_16x16x32_bf16(ah[mt], bh[nt], acc[mt][nt], 0, 0, 0);
            }
        p ^= 1;
    }
#pragma unroll
    for (int mt = 0; mt < 2; ++mt)
#pragma unroll
        for (int nt = 0; nt < 2; ++nt) {
            int col = n0 + wn * 32 + nt * 16 + l15;
            float bb = bias ? bias[col] : 0.f;
#pragma unroll
            for (int reg = 0; reg < 4; ++reg) {
                int row = m0 + wm * 32 + mt * 16 + quad * 4 + reg;
                float v = acc[mt][nt][reg] + bb;
                if (outF) outF[(size_t)row * N + col] = v;
                if (sh) {
                    if (col < scols) {
                        us h, l;
                        split1(v, h, l);
                        size_t o = (size_t)row * scols + col;
                        sh[o] = h;
                        sl[o] = l;
                    } else if (bh16) {
                        bh16[(size_t)row * scols + (col - scols)] = fp16out ? f2h(v) : f2b(v);
                    }
                }
            }
        }
}

// ---------- reduce partials + bias; f32 out + hi/lo split (col<scols) + 16-bit (col>=scols) ----------
__global__ __launch_bounds__(256)
void k_reduce(const float* __restrict__ part, int S, int MN, int N,
              const float* __restrict__ bias, float* __restrict__ outF,
              us* __restrict__ sh, us* __restrict__ sl, int scols,
              us* __restrict__ bh16, int fp16out) {
    int i = blockIdx.x * 256 + threadIdx.x;
    if (i >= MN) return;
    float v = 0.f;
    for (int s = 0; s < S; ++s) v += part[(size_t)s * MN + i];
    int row = i / N, col = i - row * N;
    if (bias) v += bias[col];
    if (outF) outF[i] = v;
    if (col < scols) {
        if (sh) {
            us h, l;
            split1(v, h, l);
            size_t o = (size_t)row * scols + col;
            sh[o] = h;
            sl[o] = l;
        }
    } else if (bh16) {
        bh16[(size_t)row * scols + (col - scols)] = fp16out ? f2h(v) : f2b(v);
    }
}

// ---------------- P-GEMM v13: 8-phase-template port (256x256 tile, 8 waves, BK=32, 3-slot ring) ----------------
// R5 diagnosis: v10's 655 TF == the guide's measured 2-phase plateau (m233: 607 TF;
// stage+vmcnt+barrier overhead amortizable ONLY by the full fine-interleaved counted-vmcnt
// schedule — partial grafts null, matching v9/v11/v12's falsifications).
// Structure: 512 thr / 8 waves (2Mj x 4Nw); block tile 256j x 256w, fixed c; grid 3jb x 4wb x 64c.
// BK=32 steps (24), LDS ring of 3 slots x (A 16KB + B 16KB) in the conflict-free chunk-major
// [q=4][row=256][8] layout (0 conflicts, counter-verified in all prior rounds).
// Per step: entry {vmcnt(4) counted, s_barrier, sched_barrier} then 2 phases of
// {ds_read frags | issue 2 gload_lds for step s+2 | lgkmcnt(0)+sched_barrier | setprio(1)
//  16 MFMA setprio(0)} with a mid-step s_barrier.
// WAR-safe: slot written during step s = slot(s-1); every wave's s-1 reads retired
// (its own lgkmcnt(0)) before its entry barrier. vmcnt(4)+barrier => slot(s) fully landed.
// Numerics identical to v10: scale A(W1c)-frags by lv in regs, same MFMA orientation.
__global__ __launch_bounds__(512, 1)
void k_mfma13(const us* __restrict__ t1b,   // (1024,768) fp16   (B side, n=w)
              const us* __restrict__ W1ct,  // (768,768) fp16 [j][k]  (A side, m=j)
              const us* __restrict__ lb1b,  // (64,768) fp16
              const float* __restrict__ Aw, // (1024,768) f32
              const float* __restrict__ Bc, // (64,768) f32 (includes b1)
              const float* __restrict__ W2, // (768,3) f32
              float* __restrict__ scr) {    // (3,1024,64,3) f32 partials
    __shared__ __align__(16) us RA[3][8192];   // slot: [q=4][row=256][8] fp16, 16 KB
    __shared__ __align__(16) us RB[3][8192];
    __shared__ __align__(16) us lbs[Hd];       // lb1 row c (1.5 KB)
    __shared__ float sred[256 * 3];

    const int tid = threadIdx.x, wave = tid >> 6, lane = tid & 63;
    const int quad = lane >> 4, l15 = lane & 15;
    const int wm2 = wave >> 2, wn4 = wave & 3;   // 2 x 4 wave grid (m=j, n=w)

    // decode: 768 blocks = 8 xcd * 96; per xcd: 12 (jb,wb) tiles x 8 consecutive c
    const int b = blockIdx.x;
    const int xcd = b & 7, s5 = b >> 3;        // s5 0..95
    const int cl = s5 & 7, idx = s5 >> 3;      // idx 0..11
    const int jb = idx % 3, wb = idx / 3;      // jb 0..2 (j tile), wb 0..3 (w tile)
    const int c  = xcd * 8 + cl;

    for (int i = tid; i < 256 * 3; i += 512) sred[i] = 0.f;
    if (tid < 96) *(short8*)&lbs[tid * 8] = *(const short8*)&lb1b[(size_t)c * Hd + tid * 8];

    // staging map: wave issues per step 2 A-insts + 2 B-insts (1 KB each):
    //   inst (q = wave&3, r64 = (wave>>2)*2 + j), lane -> row r64*64+lane
    const int q = wave & 3, rh = wave >> 2;
    const us* gA0 = W1ct + (size_t)(jb * 256 + (rh * 2 + 0) * 64 + lane) * Hd + q * 8;
    const us* gA1 = W1ct + (size_t)(jb * 256 + (rh * 2 + 1) * 64 + lane) * Hd + q * 8;
    const us* gB0 = t1b + (size_t)(wb * 256 + (rh * 2 + 0) * 64 + lane) * Hd + q * 8;
    const us* gB1 = t1b + (size_t)(wb * 256 + (rh * 2 + 1) * 64 + lane) * Hd + q * 8;
    const int dA0 = q * 2048 + (rh * 2 + 0) * 512;   // us offsets
    const int dA1 = q * 2048 + (rh * 2 + 1) * 512;

    f32x4 acc[8][4];
#pragma unroll
    for (int mf = 0; mf < 8; ++mf)
#pragma unroll
        for (int nf = 0; nf < 4; ++nf) acc[mf][nf] = (f32x4){0.f, 0.f, 0.f, 0.f};

    auto stagePh = [&](int slot, int k0, int j) {
        if (j == 0) { gload16(gA0 + k0, &RA[slot][dA0]); gload16(gB0 + k0, &RB[slot][dA0]); }
        else        { gload16(gA1 + k0, &RA[slot][dA1]); gload16(gB1 + k0, &RB[slot][dA1]); }
    };

    // fragment read bases (us): elem (q=quad, row) at quad*2048 + row*8
    const int rbA = quad * 2048 + (wm2 * 128 + l15) * 8;   // + mf*128
    const int rbB = quad * 2048 + (wn4 * 64 + l15) * 8;    // + nf*128

    __syncthreads();   // lbs/sred visible; VMEM queue drained -> vmcnt counting starts clean

    stagePh(0, 0, 0);  stagePh(0, 0, 1);     // step 0
    stagePh(1, 32, 0); stagePh(1, 32, 1);    // step 1  (8 loads in flight)

#pragma unroll
    for (int s = 0; s < 24; ++s) {
        const int slot = s % 3;
        if (s < 23) asm volatile("s_waitcnt vmcnt(4)" ::: "memory");  // step-s loads landed
        else        asm volatile("s_waitcnt vmcnt(0)" ::: "memory");
        __builtin_amdgcn_s_barrier();
        __builtin_amdgcn_sched_barrier(0);
        // ---- phase A: mf 0-3 ----
        short8 bF[4], aF[4];
        short8 lv = *(const short8*)&lbs[s * 32 + quad * 8];
#pragma unroll
        for (int nf = 0; nf < 4; ++nf) bF[nf] = *(const short8*)&RB[slot][rbB + nf * 128];
#pragma unroll
        for (int i = 0; i < 4; ++i) aF[i] = *(const short8*)&RA[slot][rbA + i * 128];
        if (s + 2 < 24) stagePh((s + 2) % 3, (s + 2) * 32, 0);
        asm volatile("s_waitcnt lgkmcnt(0)" ::: "memory");
        __builtin_amdgcn_sched_barrier(0);
        __builtin_amdgcn_s_setprio(1);
#pragma unroll
        for (int i = 0; i < 4; ++i) {
            short8 aS = hmul8(aF[i], lv);
#pragma unroll
            for (int nf = 0; nf < 4; ++nf)
                acc[i][nf] = __builtin_amdgcn_mfma_f32_16x16x32_f16(
                    __builtin_bit_cast(half8, aS),
                    __builtin_bit_cast(half8, bF[nf]), acc[i][nf], 0, 0, 0);
        }
        __builtin_amdgcn_s_setprio(0);
        __builtin_amdgcn_s_barrier();
        // ---- phase B: mf 4-7 ----
#pragma unroll
        for (int i = 0; i < 4; ++i) aF[i] = *(const short8*)&RA[slot][rbA + (4 + i) * 128];
        if (s + 2 < 24) stagePh((s + 2) % 3, (s + 2) * 32, 1);
        asm volatile("s_waitcnt lgkmcnt(0)" ::: "memory");
        __builtin_amdgcn_sched_barrier(0);
        __builtin_amdgcn_s_setprio(1);
#pragma unroll
        for (int i = 0; i < 4; ++i) {
            short8 aS = hmul8(aF[i], lv);
#pragma unroll
            for (int nf = 0; nf < 4; ++nf)
                acc[4 + i][nf] = __builtin_amdgcn_mfma_f32_16x16x32_f16(
                    __builtin_bit_cast(half8, aS),
                    __builtin_bit_cast(half8, bF[nf]), acc[4 + i][nf], 0, 0, 0);
        }
        __builtin_amdgcn_s_setprio(0);
    }

    // ---- epilogue: h = relu(P + Aw[w,j] + Bc[c,j]); s[w][r] += h*W2[j,r] ----
    // j = jb*256 + wm2*128 + mf*16 + quad*4 + reg ; w = wb*256 + wn4*64 + nf*16 + l15
    float sv[4][3];
#pragma unroll
    for (int nf = 0; nf < 4; ++nf)
#pragma unroll
        for (int r = 0; r < 3; ++r) sv[nf][r] = 0.f;

#pragma unroll
    for (int mf = 0; mf < 8; ++mf) {
        const int jg = jb * 256 + wm2 * 128 + mf * 16 + quad * 4;
        float4 bc4 = *(const float4*)&Bc[(size_t)c * Hd + jg];
        float bcv[4] = {bc4.x, bc4.y, bc4.z, bc4.w};
        float w2v[4][3];
#pragma unroll
        for (int reg = 0; reg < 4; ++reg)
#pragma unroll
            for (int r = 0; r < 3; ++r) w2v[reg][r] = W2[(jg + reg) * 3 + r];
#pragma unroll
        for (int nf = 0; nf < 4; ++nf) {
            const int w = wb * 256 + wn4 * 64 + nf * 16 + l15;
            float4 a4 = *(const float4*)&Aw[(size_t)w * Hd + jg];
            float av[4] = {a4.x, a4.y, a4.z, a4.w};
#pragma unroll
            for (int reg = 0; reg < 4; ++reg) {
                float h = acc[mf][nf][reg] + av[reg] + bcv[reg];
                h = h > 0.f ? h : 0.f;
                sv[nf][0] += h * w2v[reg][0];
                sv[nf][1] += h * w2v[reg][1];
                sv[nf][2] += h * w2v[reg][2];
            }
        }
    }
#pragma unroll
    for (int nf = 0; nf < 4; ++nf) {
#pragma unroll
        for (int r = 0; r < 3; ++r) {
            float s = sv[nf][r];
            s += __shfl_xor(s, 16);
            s += __shfl_xor(s, 32);
            sv[nf][r] = s;
        }
        if (quad == 0) {
            const int wl = wn4 * 64 + nf * 16 + l15;
            atomicAdd(&sred[wl * 3 + 0], sv[nf][0]);   // 2-way contention (wm2)
            atomicAdd(&sred[wl * 3 + 1], sv[nf][1]);
            atomicAdd(&sred[wl * 3 + 2], sv[nf][2]);
        }
    }
    __syncthreads();

    // store to per-jb scratch slab (disjoint across blocks)
    float* slab = scr + (size_t)jb * (1024 * Cn * 3);
    for (int i = tid; i < 256 * 3; i += 512) {
        int wl = i / 3, r = i - wl * 3;
        slab[((size_t)(wb * 256 + wl) * Cn + c) * 3 + r] = sred[i];
    }
}

// ---------- final: out = b2 + sum_jb scr[jb] ----------
__global__ __launch_bounds__(256)
void k_scores(const float* __restrict__ scr, const float* __restrict__ b2,
              float* __restrict__ out, int n) {
    int i = blockIdx.x * 256 + threadIdx.x;
    if (i >= n) return;
    float v = b2[i % 3];
#pragma unroll
    for (int s = 0; s < 3; ++s) v += scr[(size_t)s * n + i];
    out[i] = v;
}

extern "C" void kernel_launch(void* const* d_in, const int* in_sizes, int n_in,
                              void* d_out, int out_size, void* d_ws, size_t ws_size,
                              hipStream_t stream) {
    const float* tok    = (const float*)d_in[0];
    const int*   wmask  = (const int*)d_in[1];
    const float* labe   = (const float*)d_in[3];
    const float* W_tok  = (const float*)d_in[4];
    const float* b_tok  = (const float*)d_in[5];
    const float* W_lab  = (const float*)d_in[6];
    const float* b_lab  = (const float*)d_in[7];
    const float* W1     = (const float*)d_in[8];
    const float* b1     = (const float*)d_in[9];
    const float* W2     = (const float*)d_in[10];
    const float* b2     = (const float*)d_in[11];
    float* out = (float*)d_out;

    const int L  = in_sizes[1];
    const int Wd = out_size / (Cn * 3);   // 1024

    char* ws = (char*)d_ws;
    size_t off = 0;
    auto alloc = [&](size_t bytes) { char* p = ws + off; off += (bytes + 255) & ~(size_t)255; return p; };
    // ---- persistent region ----
    int*   widx  = (int*)alloc(4096);
    float* Abuf  = (float*)alloc((size_t)Wd * Hd * 4);
    float* Bbuf  = (float*)alloc((size_t)Cn * Hd * 4);
    us* W1ct  = (us*)alloc((size_t)Hd * Hd * 2);   // fp16
    us* W1cl  = (us*)alloc((size_t)Hd * Hd * 2);   // unused
    us* t1b   = (us*)alloc((size_t)Wd * Hd * 2);   // fp16
    us* lb1b  = (us*)alloc((size_t)Cn * Hd * 2);   // fp16
    float* scr = (float*)alloc((size_t)3 * Wd * Cn * 3 * 4);   // 2.36 MB partials
    // ---- scratch region ----
    us* WtTh  = (us*)alloc((size_t)H2 * Hd * 2);
    us* WtTl  = (us*)alloc((size_t)H2 * Hd * 2);
    us* WlTh  = (us*)alloc((size_t)H2 * Hd * 2);
    us* WlTl  = (us*)alloc((size_t)H2 * Hd * 2);
    us* W1aTh = (us*)alloc((size_t)Hd * Hd * 2);
    us* W1aTl = (us*)alloc((size_t)Hd * Hd * 2);
    us* W1bTh = (us*)alloc((size_t)Hd * Hd * 2);
    us* W1bTl = (us*)alloc((size_t)Hd * Hd * 2);
    us* weh   = (us*)alloc((size_t)Wd * Hd * 2);
    us* wel   = (us*)alloc((size_t)Wd * Hd * 2);
    us* lah   = (us*)alloc((size_t)Cn * Hd * 2);
    us* lal   = (us*)alloc((size_t)Cn * Hd * 2);
    us* t0h   = (us*)alloc((size_t)Wd * Hd * 2);
    us* t0l   = (us*)alloc((size_t)Wd * Hd * 2);
    us* lb0h  = (us*)alloc((size_t)Cn * Hd * 2);
    us* lb0l  = (us*)alloc((size_t)Cn * Hd * 2);
    float* part = (float*)alloc((size_t)8 * Cn * H2 * 4);

    // 1) init + scatter + we split
    k_init<<<(Wd + 255) / 256, 256, 0, stream>>>(widx, Wd);
    k_scatter<<<(L + 255) / 256, 256, 0, stream>>>(wmask, widx, L, Wd);
    k_build_we_split<<<(Wd * 192 + 255) / 256, 256, 0, stream>>>((const float4*)tok, widx, weh, wel, Wd);

    // 2) batched weight transpose+split (W1c -> fp16)
    TSArgs ts;
    ts.src[0] = W_tok;  ts.th[0] = WtTh;  ts.tl[0] = WtTl;  ts.ld[0] = H2; ts.N[0] = H2; ts.fmt[0] = 0;
    ts.src[1] = W_lab;  ts.th[1] = WlTh;  ts.tl[1] = WlTl;  ts.ld[1] = H2; ts.N[1] = H2; ts.fmt[1] = 0;
    ts.src[2] = W1;                         ts.th[2] = W1aTh; ts.tl[2] = W1aTl; ts.ld[2] = Hd; ts.N[2] = Hd; ts.fmt[2] = 0;
    ts.src[3] = W1 + (size_t)Hd * Hd;       ts.th[3] = W1bTh; ts.tl[3] = W1bTl; ts.ld[3] = Hd; ts.N[3] = Hd; ts.fmt[3] = 0;
    ts.src[4] = W1 + (size_t)2 * Hd * Hd;   ts.th[4] = W1ct;  ts.tl[4] = W1cl;  ts.ld[4] = Hd; ts.N[4] = Hd; ts.fmt[4] = 1;
    k_tsplit<<<dim3(H2 / 64, Hd / 64, 5), 256, 0, stream>>>(ts);

    // 3) label emb split
    k_split<<<(Cn * Hd / 4 + 255) / 256, 256, 0, stream>>>(labe, Hd, Hd, lah, lal, Cn * Hd / 4);

    // 4) t = we @ W_tok + b_tok -> fused t0 hi/lo + t1b fp16
    k_gemm3<<<dim3(H2 / 64, Wd / 64), 256, 0, stream>>>(weh, wel, WtTh, WtTl, b_tok,
                                                        nullptr, t0h, t0l, t1b, 1, Hd, H2, Hd);

    // 5) lb = labe @ W_lab + b_lab (64x1536), z=8 -> reduce (lb0 split + lb1b fp16)
    k_gemm2<<<dim3(H2 / 64, 1, 8), 256, 0, stream>>>(lah, lal, WlTh, WlTl, part, Cn, H2, Hd);
    k_reduce<<<(Cn * H2 + 255) / 256, 256, 0, stream>>>(part, 8, Cn * H2, H2, b_lab, nullptr, lb0h, lb0l, Hd, lb1b, 1);

    // 6) Aw = t0 @ W1a (1024x768) -> fused f32 write
    k_gemm3<<<dim3(Hd / 64, Wd / 64), 256, 0, stream>>>(t0h, t0l, W1aTh, W1aTl, nullptr,
                                                        Abuf, nullptr, nullptr, nullptr, 0, 0, Hd, Hd);

    // 7) Bc = lb0 @ W1b + b1 (64x768), z=8 -> reduce
    k_gemm2<<<dim3(Hd / 64, 1, 8), 256, 0, stream>>>(lb0h, lb0l, W1bTh, W1bTl, part, Cn, Hd, Hd);
    k_reduce<<<(Cn * Hd + 255) / 256, 256, 0, stream>>>(part, 8, Cn * Hd, Hd, b1, Bbuf, nullptr, nullptr, Hd, nullptr, 0);

    // 8) fused fp16 P-GEMM v13 (8-phase-template structure) -> scratch
    k_mfma13<<<768, 512, 0, stream>>>(t1b, W1ct, lb1b, Abuf, Bbuf, W2, scr);

    // 9) out = b2 + sum_jb scr
    k_scores<<<(Wd * Cn * 3 + 255) / 256, 256, 0, stream>>>(scr, b2, out, Wd * Cn * 3);
}

// Round 7
// 293.105 us; speedup vs baseline: 1.2965x; 1.0535x over previous
//
#include <hip/hip_runtime.h>
#include <hip/hip_bf16.h>

static constexpr int Hd = 768;    // H
static constexpr int H2 = 1536;   // 2H
static constexpr int Cn = 64;     // C (labels)

typedef __attribute__((ext_vector_type(8))) short short8;
typedef __attribute__((ext_vector_type(8))) _Float16 half8;
typedef __attribute__((ext_vector_type(4))) float f32x4;
typedef unsigned short us;

__device__ inline void split1(float x, us& h, us& l) {
    __hip_bfloat16 hb = __float2bfloat16(x);
    float hf = __bfloat162float(hb);
    __hip_bfloat16 lb_ = __float2bfloat16(x - hf);
    h = *reinterpret_cast<us*>(&hb);
    l = *reinterpret_cast<us*>(&lb_);
}

__device__ inline us f2b(float x) {
    __hip_bfloat16 b = __float2bfloat16(x);
    return *reinterpret_cast<us*>(&b);
}

__device__ inline us f2h(float x) {
    _Float16 h = (_Float16)x;
    return *reinterpret_cast<us*>(&h);
}

// packed fp16 elementwise product: 4x v_pk_mul_f16
__device__ inline short8 hmul8(short8 a, short8 b) {
    half8 x = __builtin_bit_cast(half8, a);
    half8 y = __builtin_bit_cast(half8, b);
    half8 r = x * y;
    return __builtin_bit_cast(short8, r);
}

__device__ inline void gload16(const void* g, void* l) {
    __builtin_amdgcn_global_load_lds(
        (const __attribute__((address_space(1))) unsigned int*)g,
        (__attribute__((address_space(3))) unsigned int*)l, 16, 0, 0);
}

// ---------------- init: widx = -1 ----------------
__global__ void k_init(int* widx, int Wd) {
    int i = blockIdx.x * 256 + threadIdx.x;
    if (i < Wd) widx[i] = -1;
}

__global__ void k_scatter(const int* __restrict__ wmask, int* widx, int L, int Wd) {
    int i = blockIdx.x * 256 + threadIdx.x;
    if (i < L) {
        int m = wmask[i];
        if (m > 0 && m <= Wd) atomicMax(&widx[m - 1], i);  // last token wins
    }
}

// build we directly as hi/lo bf16 split
__global__ void k_build_we_split(const float4* __restrict__ tok, const int* __restrict__ widx,
                                 us* __restrict__ weh, us* __restrict__ wel, int Wd) {
    int i = blockIdx.x * 256 + threadIdx.x;   // over Wd * 192
    if (i >= Wd * 192) return;
    int w = i / 192, c4 = i - w * 192;
    int idx = widx[w];
    float4 v = (idx >= 0) ? tok[idx * 192 + c4] : float4{0.f, 0.f, 0.f, 0.f};
    us hh[4], ll[4];
    split1(v.x, hh[0], ll[0]);
    split1(v.y, hh[1], ll[1]);
    split1(v.z, hh[2], ll[2]);
    split1(v.w, hh[3], ll[3]);
    size_t o = (size_t)w * Hd + c4 * 4;
    *(ushort4*)&weh[o] = ushort4{hh[0], hh[1], hh[2], hh[3]};
    *(ushort4*)&wel[o] = ushort4{ll[0], ll[1], ll[2], ll[3]};
}

// ---------- batched transpose + split: T[n][k]; fmt=0 bf16 hi/lo, fmt=1 fp16 (Th only) ----------
struct TSArgs {
    const float* src[5];
    us* th[5];
    us* tl[5];
    int ld[5];
    int N[5];
    int fmt[5];
};
__global__ __launch_bounds__(256)
void k_tsplit(TSArgs a) {
    __shared__ float tile[64][65];
    const int z = blockIdx.z;
    const int n0 = blockIdx.x * 64, k0 = blockIdx.y * 64;
    if (n0 >= a.N[z]) return;
    const float* W = a.src[z];
    const int ld = a.ld[z];
    for (int idx = threadIdx.x; idx < 4096; idx += 256) {
        int kk = idx >> 6, nn = idx & 63;
        tile[kk][nn] = W[(size_t)(k0 + kk) * ld + n0 + nn];
    }
    __syncthreads();
    us* Th = a.th[z];
    us* Tl = a.tl[z];
    const int fmt = a.fmt[z];
    for (int idx = threadIdx.x; idx < 4096; idx += 256) {
        int nn = idx >> 6, kk = idx & 63;
        size_t o = (size_t)(n0 + nn) * Hd + k0 + kk;
        if (fmt) {
            Th[o] = f2h(tile[kk][nn]);
        } else {
            us h, l;
            split1(tile[kk][nn], h, l);
            Th[o] = h;
            Tl[o] = l;
        }
    }
}

// ---------- row-major hi/lo split ----------
__global__ __launch_bounds__(256)
void k_split(const float* __restrict__ x, int lda, int cols,
             us* __restrict__ h, us* __restrict__ l, int n4) {
    int i = blockIdx.x * 256 + threadIdx.x;
    if (i >= n4) return;
    int c4 = cols >> 2;
    int row = i / c4, cc = (i - row * c4) * 4;
    float4 v = *(const float4*)&x[(size_t)row * lda + cc];
    us hh[4], ll[4];
    split1(v.x, hh[0], ll[0]);
    split1(v.y, hh[1], ll[1]);
    split1(v.z, hh[2], ll[2]);
    split1(v.w, hh[3], ll[3]);
    size_t o = (size_t)row * cols + cc;
    *(ushort4*)&h[o] = ushort4{hh[0], hh[1], hh[2], hh[3]};
    *(ushort4*)&l[o] = ushort4{ll[0], ll[1], ll[2], ll[3]};
}

// ---------- split-bf16 GEMM, LDS double-buffered, K-split partials (small Ms) ----------
__global__ __launch_bounds__(256)
void k_gemm2(const us* __restrict__ Ah, const us* __restrict__ Al,
             const us* __restrict__ BhT, const us* __restrict__ BlT,
             float* __restrict__ Cpart, int M, int N, int K) {
    __shared__ __align__(16) us S[2][4][64 * 32];
    const int tid = threadIdx.x, wave = tid >> 6, lane = tid & 63;
    const int quad = lane >> 4, l15 = lane & 15;
    const int wm = wave & 1, wn = wave >> 1;
    const int m0 = blockIdx.y * 64, n0 = blockIdx.x * 64;
    const int Ks = K / gridDim.z, kbeg = blockIdx.z * Ks, kend = kbeg + Ks;
    float* C = Cpart + (size_t)blockIdx.z * M * N;

    const int srow = wave * 16 + (lane >> 2), soff = (lane & 3) * 8;
    const size_t gaB = (size_t)(m0 + srow) * K + soff;
    const size_t gbB = (size_t)(n0 + srow) * K + soff;
    const int lo = wave * 16 * 32;

    f32x4 acc[2][2];
#pragma unroll
    for (int a = 0; a < 2; ++a)
#pragma unroll
        for (int b = 0; b < 2; ++b) acc[a][b] = (f32x4){0.f, 0.f, 0.f, 0.f};

    auto stage = [&](int p, int k0) {
        gload16(Ah + gaB + k0, &S[p][0][lo]);
        gload16(Al + gaB + k0, &S[p][1][lo]);
        gload16(BhT + gbB + k0, &S[p][2][lo]);
        gload16(BlT + gbB + k0, &S[p][3][lo]);
    };

    int p = 0;
    stage(0, kbeg);
    for (int k0 = kbeg; k0 < kend; k0 += 32) {
        __syncthreads();
        if (k0 + 32 < kend) stage(p ^ 1, k0 + 32);
        short8 ah[2], al[2], bh[2], bl[2];
#pragma unroll
        for (int mt = 0; mt < 2; ++mt) {
            int off = (wm * 32 + mt * 16 + l15) * 32 + quad * 8;
            ah[mt] = *(const short8*)&S[p][0][off];
            al[mt] = *(const short8*)&S[p][1][off];
        }
#pragma unroll
        for (int nt = 0; nt < 2; ++nt) {
            int off = (wn * 32 + nt * 16 + l15) * 32 + quad * 8;
            bh[nt] = *(const short8*)&S[p][2][off];
            bl[nt] = *(const short8*)&S[p][3][off];
        }
#pragma unroll
        for (int mt = 0; mt < 2; ++mt)
#pragma unroll
            for (int nt = 0; nt < 2; ++nt) {
                acc[mt][nt] = __builtin_amdgcn_mfma_f32_16x16x32_bf16(al[mt], bh[nt], acc[mt][nt], 0, 0, 0);
                acc[mt][nt] = __builtin_amdgcn_mfma_f32_16x16x32_bf16(ah[mt], bl[nt], acc[mt][nt], 0, 0, 0);
                acc[mt][nt] = __builtin_amdgcn_mfma_f32_16x16x32_bf16(ah[mt], bh[nt], acc[mt][nt], 0, 0, 0);
            }
        p ^= 1;
    }
#pragma unroll
    for (int mt = 0; mt < 2; ++mt)
#pragma unroll
        for (int nt = 0; nt < 2; ++nt) {
            int col = n0 + wn * 32 + nt * 16 + l15;
#pragma unroll
            for (int reg = 0; reg < 4; ++reg) {
                int row = m0 + wm * 32 + mt * 16 + quad * 4 + reg;
                C[(size_t)row * N + col] = acc[mt][nt][reg];
            }
        }
}

// ---------- split-bf16 GEMM, z=1, fused outputs (bias + f32 / hi-lo split / 16-bit) ----------
__global__ __launch_bounds__(256)
void k_gemm3(const us* __restrict__ Ah, const us* __restrict__ Al,
             const us* __restrict__ BhT, const us* __restrict__ BlT,
             const float* __restrict__ bias, float* __restrict__ outF,
             us* __restrict__ sh, us* __restrict__ sl, us* __restrict__ bh16,
             int fp16out, int scols, int N, int K) {
    __shared__ __align__(16) us S[2][4][64 * 32];
    const int tid = threadIdx.x, wave = tid >> 6, lane = tid & 63;
    const int quad = lane >> 4, l15 = lane & 15;
    const int wm = wave & 1, wn = wave >> 1;
    const int m0 = blockIdx.y * 64, n0 = blockIdx.x * 64;

    const int srow = wave * 16 + (lane >> 2), soff = (lane & 3) * 8;
    const size_t gaB = (size_t)(m0 + srow) * K + soff;
    const size_t gbB = (size_t)(n0 + srow) * K + soff;
    const int lo = wave * 16 * 32;

    f32x4 acc[2][2];
#pragma unroll
    for (int a = 0; a < 2; ++a)
#pragma unroll
        for (int b = 0; b < 2; ++b) acc[a][b] = (f32x4){0.f, 0.f, 0.f, 0.f};

    auto stage = [&](int p, int k0) {
        gload16(Ah + gaB + k0, &S[p][0][lo]);
        gload16(Al + gaB + k0, &S[p][1][lo]);
        gload16(BhT + gbB + k0, &S[p][2][lo]);
        gload16(BlT + gbB + k0, &S[p][3][lo]);
    };

    int p = 0;
    stage(0, 0);
    for (int k0 = 0; k0 < K; k0 += 32) {
        __syncthreads();
        if (k0 + 32 < K) stage(p ^ 1, k0 + 32);
        short8 ah[2], al[2], bh[2], bl[2];
#pragma unroll
        for (int mt = 0; mt < 2; ++mt) {
            int off = (wm * 32 + mt * 16 + l15) * 32 + quad * 8;
            ah[mt] = *(const short8*)&S[p][0][off];
            al[mt] = *(const short8*)&S[p][1][off];
        }
#pragma unroll
        for (int nt = 0; nt < 2; ++nt) {
            int off = (wn * 32 + nt * 16 + l15) * 32 + quad * 8;
            bh[nt] = *(const short8*)&S[p][2][off];
            bl[nt] = *(const short8*)&S[p][3][off];
        }
#pragma unroll
        for (int mt = 0; mt < 2; ++mt)
#pragma unroll
            for (int nt = 0; nt < 2; ++nt) {
                acc[mt][nt] = __builtin_amdgcn_mfma_f32_16x16x32_bf16(al[mt], bh[nt], acc[mt][nt], 0, 0, 0);
                acc[mt][nt] = __builtin_amdgcn_mfma_f32_16x16x32_bf16(ah[mt], bl[nt], acc[mt][nt], 0, 0, 0);
                acc[mt][nt] = __builtin_amdgcn_mfma_f32_16x16x32_bf16(ah[mt], bh[nt], acc[mt][nt], 0, 0, 0);
            }
        p ^= 1;
    }
#pragma unroll
    for (int mt = 0; mt < 2; ++mt)
#pragma unroll
        for (int nt = 0; nt < 2; ++nt) {
            int col = n0 + wn * 32 + nt * 16 + l15;
            float bb = bias ? bias[col] : 0.f;
#pragma unroll
            for (int reg = 0; reg < 4; ++reg) {
                int row = m0 + wm * 32 + mt * 16 + quad * 4 + reg;
                float v = acc[mt][nt][reg] + bb;
                if (outF) outF[(size_t)row * N + col] = v;
                if (sh) {
                    if (col < scols) {
                        us h, l;
                        split1(v, h, l);
                        size_t o = (size_t)row * scols + col;
                        sh[o] = h;
                        sl[o] = l;
                    } else if (bh16) {
                        bh16[(size_t)row * scols + (col - scols)] = fp16out ? f2h(v) : f2b(v);
                    }
                }
            }
        }
}

// ---------- reduce partials + bias; f32 out + hi/lo split (col<scols) + 16-bit (col>=scols) ----------
__global__ __launch_bounds__(256)
void k_reduce(const float* __restrict__ part, int S, int MN, int N,
              const float* __restrict__ bias, float* __restrict__ outF,
              us* __restrict__ sh, us* __restrict__ sl, int scols,
              us* __restrict__ bh16, int fp16out) {
    int i = blockIdx.x * 256 + threadIdx.x;
    if (i >= MN) return;
    float v = 0.f;
    for (int s = 0; s < S; ++s) v += part[(size_t)s * MN + i];
    int row = i / N, col = i - row * N;
    if (bias) v += bias[col];
    if (outF) outF[i] = v;
    if (col < scols) {
        if (sh) {
            us h, l;
            split1(v, h, l);
            size_t o = (size_t)row * scols + col;
            sh[o] = h;
            sl[o] = l;
        }
    } else if (bh16) {
        bh16[(size_t)row * scols + (col - scols)] = fp16out ? f2h(v) : f2b(v);
    }
}

// ---------------- P-GEMM v14: v13's 8-phase schedule, spill-free geometry ----------------
// R6 post-mortem: v13 spilled (arch 128 + acc 128 = 256 cap; FETCH 92MB/WRITE 116MB of
// scratch traffic). Fix: split labels across waves instead of doubling acc.
// 8 waves = 2jm x 2wn x 2cw; block tile 128j x 128w x 2 labels (v10's tile & AI:
// 128 MFMA / 16KB staged); per wave 64j x 64w x 1c -> acc 64, frags 64, ~170 live regs.
// Grid/decode = v10 (1536 blocks, wb=xcd). LDS = 3-slot ring x (8KB A + 8KB B) ~54KB.
// Schedule per 32-k step: {vmcnt(2) counted entry, s_barrier, SB(0)} then
// phase A {ds_read lv+bF[0..3]+aF[0..1] | issue A-stage s+2 | lgkm(0)+SB(0) |
// setprio(1) 8 MFMA setprio(0)}, mid s_barrier, phase B {aF[2..3] | B-stage s+2 | ...}.
// WAR-safe: slot written at step s = slot(s-1); all waves' s-1 reads retired (own
// lgkmcnt(0)) before their entry barrier. vmcnt(2)+barrier => slot(s) fully landed.
__global__ __launch_bounds__(512, 2)
void k_mfma14(const us* __restrict__ t1b,   // (1024,768) fp16   (B side, n=w)
              const us* __restrict__ W1ct,  // (768,768) fp16 [j][k]  (A side, m=j)
              const us* __restrict__ lb1b,  // (64,768) fp16
              const float* __restrict__ Aw, // (1024,768) f32
              const float* __restrict__ Bc, // (64,768) f32 (includes b1)
              const float* __restrict__ W2, // (768,3) f32
              float* __restrict__ scr) {    // (6,1024,64,3) f32 partials
    __shared__ __align__(16) us RA[3][4096];   // slot: [q=4][row=128][8] fp16, 8 KB
    __shared__ __align__(16) us RB[3][4096];
    __shared__ __align__(16) us lbs[2][Hd];    // lb1 rows c0, c0+1 (3 KB)
    __shared__ float sred[2 * 128 * 3];

    const int tid = threadIdx.x, wave = tid >> 6, lane = tid & 63;
    const int quad = lane >> 4, l15 = lane & 15;
    const int jm = wave & 1, wn = (wave >> 1) & 1, cw = wave >> 2;  // 2x2x2 wave grid

    // L2-locality decode (= v10): b = xcd + 8*(jx*32 + cp); w-tile pinned to xcd
    const int b = blockIdx.x;
    const int xcd = b & 7, slot5 = b >> 3;   // slot5 0..191
    const int jx = slot5 >> 5;               // 0..5
    const int cp = slot5 & 31;               // 0..31 (varies fastest)
    const int c0 = cp * 2;
    const int jt = jx * 128, m0 = xcd * 128;

    for (int i = tid; i < 2 * 128 * 3; i += 512) sred[i] = 0.f;
    if (tid < 192) {                          // stage lb1 rows c0,c0+1 (3 KB)
        int cc = tid / 96, o = (tid - cc * 96) * 8;
        *(short8*)&lbs[cc][o] = *(const short8*)&lb1b[(size_t)(c0 + cc) * Hd + o];
    }

    // staging map (v8/v10-verified): chunk i=wave (0..7): q=i>>1, rhalf=i&1;
    // lane -> row rhalf*64+lane; dest us = i*512. One A-inst + one B-inst per wave per step.
    const int rhalf = wave & 1, qc = wave >> 1;
    const us* gA = W1ct + (size_t)(jt + rhalf * 64 + lane) * Hd + qc * 8;
    const us* gB = t1b + (size_t)(m0 + rhalf * 64 + lane) * Hd + qc * 8;
    const int dst = wave * 512;

    f32x4 acc[4][4];
#pragma unroll
    for (int mf = 0; mf < 4; ++mf)
#pragma unroll
        for (int nf = 0; nf < 4; ++nf) acc[mf][nf] = (f32x4){0.f, 0.f, 0.f, 0.f};

    // fragment read bases (us): elem (q=quad,row) at quad*1024 + row*8
    const int rbA = quad * 1024 + (jm * 64 + l15) * 8;   // + mf*128
    const int rbB = quad * 1024 + (wn * 64 + l15) * 8;   // + nf*128

    __syncthreads();   // lbs/sred visible; VMEM queue clean

    // prologue: steps 0,1 staged (2 insts/wave each -> 4 outstanding)
    gload16(gA + 0,  &RA[0][dst]);  gload16(gB + 0,  &RB[0][dst]);
    gload16(gA + 32, &RA[1][dst]);  gload16(gB + 32, &RB[1][dst]);

#pragma unroll
    for (int s = 0; s < 24; ++s) {
        const int sl = s % 3;
        if (s < 23) asm volatile("s_waitcnt vmcnt(2)" ::: "memory");  // step-s landed
        else        asm volatile("s_waitcnt vmcnt(0)" ::: "memory");
        __builtin_amdgcn_s_barrier();
        __builtin_amdgcn_sched_barrier(0);
        // ---- phase A: mf 0-1 ----
        short8 lv = *(const short8*)&lbs[cw][s * 32 + quad * 8];
        short8 bF[4], aF[4];
#pragma unroll
        for (int nf = 0; nf < 4; ++nf) bF[nf] = *(const short8*)&RB[sl][rbB + nf * 128];
        aF[0] = *(const short8*)&RA[sl][rbA + 0 * 128];
        aF[1] = *(const short8*)&RA[sl][rbA + 1 * 128];
        if (s + 2 < 24) gload16(gA + (s + 2) * 32, &RA[(s + 2) % 3][dst]);
        asm volatile("s_waitcnt lgkmcnt(0)" ::: "memory");
        __builtin_amdgcn_sched_barrier(0);
        __builtin_amdgcn_s_setprio(1);
#pragma unroll
        for (int mf = 0; mf < 2; ++mf) {
            short8 aS = hmul8(aF[mf], lv);
#pragma unroll
            for (int nf = 0; nf < 4; ++nf)
                acc[mf][nf] = __builtin_amdgcn_mfma_f32_16x16x32_f16(
                    __builtin_bit_cast(half8, aS),
                    __builtin_bit_cast(half8, bF[nf]), acc[mf][nf], 0, 0, 0);
        }
        __builtin_amdgcn_s_setprio(0);
        __builtin_amdgcn_s_barrier();
        // ---- phase B: mf 2-3 ----
        aF[2] = *(const short8*)&RA[sl][rbA + 2 * 128];
        aF[3] = *(const short8*)&RA[sl][rbA + 3 * 128];
        if (s + 2 < 24) gload16(gB + (s + 2) * 32, &RB[(s + 2) % 3][dst]);
        asm volatile("s_waitcnt lgkmcnt(0)" ::: "memory");
        __builtin_amdgcn_sched_barrier(0);
        __builtin_amdgcn_s_setprio(1);
#pragma unroll
        for (int mf = 2; mf < 4; ++mf) {
            short8 aS = hmul8(aF[mf], lv);
#pragma unroll
            for (int nf = 0; nf < 4; ++nf)
                acc[mf][nf] = __builtin_amdgcn_mfma_f32_16x16x32_f16(
                    __builtin_bit_cast(half8, aS),
                    __builtin_bit_cast(half8, bF[nf]), acc[mf][nf], 0, 0, 0);
        }
        __builtin_amdgcn_s_setprio(0);
    }

    // ---- epilogue (label c0+cw): h = relu(P + Aw + Bc); s[w][r] += h*W2[j][r] ----
    // j = jt + jm*64 + mf*16 + quad*4 + reg ; w = m0 + wn*64 + nf*16 + l15
    const int cme = c0 + cw;
    float bcv[4][4], w2v[4][4][3];
#pragma unroll
    for (int mf = 0; mf < 4; ++mf) {
        const int jg = jt + jm * 64 + mf * 16 + quad * 4;
        float4 b4 = *(const float4*)&Bc[(size_t)cme * Hd + jg];
        bcv[mf][0] = b4.x; bcv[mf][1] = b4.y; bcv[mf][2] = b4.z; bcv[mf][3] = b4.w;
#pragma unroll
        for (int reg = 0; reg < 4; ++reg)
#pragma unroll
            for (int r = 0; r < 3; ++r) w2v[mf][reg][r] = W2[(jg + reg) * 3 + r];
    }

#pragma unroll
    for (int nf = 0; nf < 4; ++nf) {
        const int w = m0 + wn * 64 + nf * 16 + l15;
        const float* awp = Aw + (size_t)w * Hd + jt + jm * 64;
        float s0 = 0.f, s1 = 0.f, s2 = 0.f;
#pragma unroll
        for (int mf = 0; mf < 4; ++mf) {
            float4 a4 = *(const float4*)&awp[mf * 16 + quad * 4];
            float av[4] = {a4.x, a4.y, a4.z, a4.w};
#pragma unroll
            for (int reg = 0; reg < 4; ++reg) {
                float h = acc[mf][nf][reg] + av[reg] + bcv[mf][reg];
                h = h > 0.f ? h : 0.f;
                s0 += h * w2v[mf][reg][0];
                s1 += h * w2v[mf][reg][1];
                s2 += h * w2v[mf][reg][2];
            }
        }
        s0 += __shfl_xor(s0, 16); s0 += __shfl_xor(s0, 32);
        s1 += __shfl_xor(s1, 16); s1 += __shfl_xor(s1, 32);
        s2 += __shfl_xor(s2, 16); s2 += __shfl_xor(s2, 32);
        if (quad == 0) {
            const int wl = wn * 64 + nf * 16 + l15;
            atomicAdd(&sred[cw * 384 + wl * 3 + 0], s0);   // 2-way contention (jm)
            atomicAdd(&sred[cw * 384 + wl * 3 + 1], s1);
            atomicAdd(&sred[cw * 384 + wl * 3 + 2], s2);
        }
    }
    __syncthreads();

    // non-atomic store to per-jx scratch slot (disjoint across blocks)
    float* slab = scr + ((size_t)jx * 1024 * Cn + (size_t)m0 * Cn) * 3;
    for (int i = tid; i < 2 * 128 * 3; i += 512) {
        int cc = i / 384, j = i - cc * 384;
        int wl = j / 3, r = j - wl * 3;
        slab[((size_t)wl * Cn + (c0 + cc)) * 3 + r] = sred[i];
    }
}

// ---------- final: out = b2 + sum_jx scr[jx] ----------
__global__ __launch_bounds__(256)
void k_scores(const float* __restrict__ scr, const float* __restrict__ b2,
              float* __restrict__ out, int n) {
    int i = blockIdx.x * 256 + threadIdx.x;
    if (i >= n) return;
    float v = b2[i % 3];
#pragma unroll
    for (int s = 0; s < 6; ++s) v += scr[(size_t)s * n + i];
    out[i] = v;
}

extern "C" void kernel_launch(void* const* d_in, const int* in_sizes, int n_in,
                              void* d_out, int out_size, void* d_ws, size_t ws_size,
                              hipStream_t stream) {
    const float* tok    = (const float*)d_in[0];
    const int*   wmask  = (const int*)d_in[1];
    const float* labe   = (const float*)d_in[3];
    const float* W_tok  = (const float*)d_in[4];
    const float* b_tok  = (const float*)d_in[5];
    const float* W_lab  = (const float*)d_in[6];
    const float* b_lab  = (const float*)d_in[7];
    const float* W1     = (const float*)d_in[8];
    const float* b1     = (const float*)d_in[9];
    const float* W2     = (const float*)d_in[10];
    const float* b2     = (const float*)d_in[11];
    float* out = (float*)d_out;

    const int L  = in_sizes[1];
    const int Wd = out_size / (Cn * 3);   // 1024

    char* ws = (char*)d_ws;
    size_t off = 0;
    auto alloc = [&](size_t bytes) { char* p = ws + off; off += (bytes + 255) & ~(size_t)255; return p; };
    // ---- persistent region ----
    int*   widx  = (int*)alloc(4096);
    float* Abuf  = (float*)alloc((size_t)Wd * Hd * 4);
    float* Bbuf  = (float*)alloc((size_t)Cn * Hd * 4);
    us* W1ct  = (us*)alloc((size_t)Hd * Hd * 2);   // fp16
    us* W1cl  = (us*)alloc((size_t)Hd * Hd * 2);   // unused
    us* t1b   = (us*)alloc((size_t)Wd * Hd * 2);   // fp16
    us* lb1b  = (us*)alloc((size_t)Cn * Hd * 2);   // fp16
    float* scr = (float*)alloc((size_t)6 * Wd * Cn * 3 * 4);   // 4.72 MB partials
    // ---- scratch region ----
    us* WtTh  = (us*)alloc((size_t)H2 * Hd * 2);
    us* WtTl  = (us*)alloc((size_t)H2 * Hd * 2);
    us* WlTh  = (us*)alloc((size_t)H2 * Hd * 2);
    us* WlTl  = (us*)alloc((size_t)H2 * Hd * 2);
    us* W1aTh = (us*)alloc((size_t)Hd * Hd * 2);
    us* W1aTl = (us*)alloc((size_t)Hd * Hd * 2);
    us* W1bTh = (us*)alloc((size_t)Hd * Hd * 2);
    us* W1bTl = (us*)alloc((size_t)Hd * Hd * 2);
    us* weh   = (us*)alloc((size_t)Wd * Hd * 2);
    us* wel   = (us*)alloc((size_t)Wd * Hd * 2);
    us* lah   = (us*)alloc((size_t)Cn * Hd * 2);
    us* lal   = (us*)alloc((size_t)Cn * Hd * 2);
    us* t0h   = (us*)alloc((size_t)Wd * Hd * 2);
    us* t0l   = (us*)alloc((size_t)Wd * Hd * 2);
    us* lb0h  = (us*)alloc((size_t)Cn * Hd * 2);
    us* lb0l  = (us*)alloc((size_t)Cn * Hd * 2);
    float* part = (float*)alloc((size_t)8 * Cn * H2 * 4);

    // 1) init + scatter + we split
    k_init<<<(Wd + 255) / 256, 256, 0, stream>>>(widx, Wd);
    k_scatter<<<(L + 255) / 256, 256, 0, stream>>>(wmask, widx, L, Wd);
    k_build_we_split<<<(Wd * 192 + 255) / 256, 256, 0, stream>>>((const float4*)tok, widx, weh, wel, Wd);

    // 2) batched weight transpose+split (W1c -> fp16)
    TSArgs ts;
    ts.src[0] = W_tok;  ts.th[0] = WtTh;  ts.tl[0] = WtTl;  ts.ld[0] = H2; ts.N[0] = H2; ts.fmt[0] = 0;
    ts.src[1] = W_lab;  ts.th[1] = WlTh;  ts.tl[1] = WlTl;  ts.ld[1] = H2; ts.N[1] = H2; ts.fmt[1] = 0;
    ts.src[2] = W1;                         ts.th[2] = W1aTh; ts.tl[2] = W1aTl; ts.ld[2] = Hd; ts.N[2] = Hd; ts.fmt[2] = 0;
    ts.src[3] = W1 + (size_t)Hd * Hd;       ts.th[3] = W1bTh; ts.tl[3] = W1bTl; ts.ld[3] = Hd; ts.N[3] = Hd; ts.fmt[3] = 0;
    ts.src[4] = W1 + (size_t)2 * Hd * Hd;   ts.th[4] = W1ct;  ts.tl[4] = W1cl;  ts.ld[4] = Hd; ts.N[4] = Hd; ts.fmt[4] = 1;
    k_tsplit<<<dim3(H2 / 64, Hd / 64, 5), 256, 0, stream>>>(ts);

    // 3) label emb split
    k_split<<<(Cn * Hd / 4 + 255) / 256, 256, 0, stream>>>(labe, Hd, Hd, lah, lal, Cn * Hd / 4);

    // 4) t = we @ W_tok + b_tok -> fused t0 hi/lo + t1b fp16
    k_gemm3<<<dim3(H2 / 64, Wd / 64), 256, 0, stream>>>(weh, wel, WtTh, WtTl, b_tok,
                                                        nullptr, t0h, t0l, t1b, 1, Hd, H2, Hd);

    // 5) lb = labe @ W_lab + b_lab (64x1536), z=8 -> reduce (lb0 split + lb1b fp16)
    k_gemm2<<<dim3(H2 / 64, 1, 8), 256, 0, stream>>>(lah, lal, WlTh, WlTl, part, Cn, H2, Hd);
    k_reduce<<<(Cn * H2 + 255) / 256, 256, 0, stream>>>(part, 8, Cn * H2, H2, b_lab, nullptr, lb0h, lb0l, Hd, lb1b, 1);

    // 6) Aw = t0 @ W1a (1024x768) -> fused f32 write
    k_gemm3<<<dim3(Hd / 64, Wd / 64), 256, 0, stream>>>(t0h, t0l, W1aTh, W1aTl, nullptr,
                                                        Abuf, nullptr, nullptr, nullptr, 0, 0, Hd, Hd);

    // 7) Bc = lb0 @ W1b + b1 (64x768), z=8 -> reduce
    k_gemm2<<<dim3(Hd / 64, 1, 8), 256, 0, stream>>>(lb0h, lb0l, W1bTh, W1bTl, part, Cn, Hd, Hd);
    k_reduce<<<(Cn * Hd + 255) / 256, 256, 0, stream>>>(part, 8, Cn * Hd, Hd, b1, Bbuf, nullptr, nullptr, Hd, nullptr, 0);

    // 8) fused fp16 P-GEMM v14 (8-phase schedule, spill-free: acc 64, labels across waves)
    k_mfma14<<<1536, 512, 0, stream>>>(t1b, W1ct, lb1b, Abuf, Bbuf, W2, scr);

    // 9) out = b2 + sum_jx scr
    k_scores<<<(Wd * Cn * 3 + 255) / 256, 256, 0, stream>>>(scr, b2, out, Wd * Cn * 3);
}

// Round 8
// 287.612 us; speedup vs baseline: 1.3213x; 1.0191x over previous
//
#include <hip/hip_runtime.h>
#include <hip/hip_bf16.h>

static constexpr int Hd = 768;    // H
static constexpr int H2 = 1536;   // 2H
static constexpr int Cn = 64;     // C (labels)

typedef __attribute__((ext_vector_type(8))) short short8;
typedef __attribute__((ext_vector_type(8))) _Float16 half8;
typedef __attribute__((ext_vector_type(4))) float f32x4;
typedef unsigned short us;

__device__ inline void split1(float x, us& h, us& l) {
    __hip_bfloat16 hb = __float2bfloat16(x);
    float hf = __bfloat162float(hb);
    __hip_bfloat16 lb_ = __float2bfloat16(x - hf);
    h = *reinterpret_cast<us*>(&hb);
    l = *reinterpret_cast<us*>(&lb_);
}

__device__ inline us f2b(float x) {
    __hip_bfloat16 b = __float2bfloat16(x);
    return *reinterpret_cast<us*>(&b);
}

__device__ inline us f2h(float x) {
    _Float16 h = (_Float16)x;
    return *reinterpret_cast<us*>(&h);
}

// packed fp16 elementwise product: 4x v_pk_mul_f16
__device__ inline short8 hmul8(short8 a, short8 b) {
    half8 x = __builtin_bit_cast(half8, a);
    half8 y = __builtin_bit_cast(half8, b);
    half8 r = x * y;
    return __builtin_bit_cast(short8, r);
}

__device__ inline void gload16(const void* g, void* l) {
    __builtin_amdgcn_global_load_lds(
        (const __attribute__((address_space(1))) unsigned int*)g,
        (__attribute__((address_space(3))) unsigned int*)l, 16, 0, 0);
}

// ---------------- init: widx = -1 ----------------
__global__ void k_init(int* widx, int Wd) {
    int i = blockIdx.x * 256 + threadIdx.x;
    if (i < Wd) widx[i] = -1;
}

__global__ void k_scatter(const int* __restrict__ wmask, int* widx, int L, int Wd) {
    int i = blockIdx.x * 256 + threadIdx.x;
    if (i < L) {
        int m = wmask[i];
        if (m > 0 && m <= Wd) atomicMax(&widx[m - 1], i);  // last token wins
    }
}

// build we directly as hi/lo bf16 split
__global__ void k_build_we_split(const float4* __restrict__ tok, const int* __restrict__ widx,
                                 us* __restrict__ weh, us* __restrict__ wel, int Wd) {
    int i = blockIdx.x * 256 + threadIdx.x;   // over Wd * 192
    if (i >= Wd * 192) return;
    int w = i / 192, c4 = i - w * 192;
    int idx = widx[w];
    float4 v = (idx >= 0) ? tok[idx * 192 + c4] : float4{0.f, 0.f, 0.f, 0.f};
    us hh[4], ll[4];
    split1(v.x, hh[0], ll[0]);
    split1(v.y, hh[1], ll[1]);
    split1(v.z, hh[2], ll[2]);
    split1(v.w, hh[3], ll[3]);
    size_t o = (size_t)w * Hd + c4 * 4;
    *(ushort4*)&weh[o] = ushort4{hh[0], hh[1], hh[2], hh[3]};
    *(ushort4*)&wel[o] = ushort4{ll[0], ll[1], ll[2], ll[3]};
}

// ---------- batched transpose + split: T[n][k]; fmt=0 bf16 hi/lo, fmt=1 fp16 (Th only) ----------
struct TSArgs {
    const float* src[5];
    us* th[5];
    us* tl[5];
    int ld[5];
    int N[5];
    int fmt[5];
};
__global__ __launch_bounds__(256)
void k_tsplit(TSArgs a) {
    __shared__ float tile[64][65];
    const int z = blockIdx.z;
    const int n0 = blockIdx.x * 64, k0 = blockIdx.y * 64;
    if (n0 >= a.N[z]) return;
    const float* W = a.src[z];
    const int ld = a.ld[z];
    for (int idx = threadIdx.x; idx < 4096; idx += 256) {
        int kk = idx >> 6, nn = idx & 63;
        tile[kk][nn] = W[(size_t)(k0 + kk) * ld + n0 + nn];
    }
    __syncthreads();
    us* Th = a.th[z];
    us* Tl = a.tl[z];
    const int fmt = a.fmt[z];
    for (int idx = threadIdx.x; idx < 4096; idx += 256) {
        int nn = idx >> 6, kk = idx & 63;
        size_t o = (size_t)(n0 + nn) * Hd + k0 + kk;
        if (fmt) {
            Th[o] = f2h(tile[kk][nn]);
        } else {
            us h, l;
            split1(tile[kk][nn], h, l);
            Th[o] = h;
            Tl[o] = l;
        }
    }
}

// ---------- row-major hi/lo split ----------
__global__ __launch_bounds__(256)
void k_split(const float* __restrict__ x, int lda, int cols,
             us* __restrict__ h, us* __restrict__ l, int n4) {
    int i = blockIdx.x * 256 + threadIdx.x;
    if (i >= n4) return;
    int c4 = cols >> 2;
    int row = i / c4, cc = (i - row * c4) * 4;
    float4 v = *(const float4*)&x[(size_t)row * lda + cc];
    us hh[4], ll[4];
    split1(v.x, hh[0], ll[0]);
    split1(v.y, hh[1], ll[1]);
    split1(v.z, hh[2], ll[2]);
    split1(v.w, hh[3], ll[3]);
    size_t o = (size_t)row * cols + cc;
    *(ushort4*)&h[o] = ushort4{hh[0], hh[1], hh[2], hh[3]};
    *(ushort4*)&l[o] = ushort4{ll[0], ll[1], ll[2], ll[3]};
}

// ---------- split-bf16 GEMM, LDS double-buffered, K-split partials (small Ms) ----------
__global__ __launch_bounds__(256)
void k_gemm2(const us* __restrict__ Ah, const us* __restrict__ Al,
             const us* __restrict__ BhT, const us* __restrict__ BlT,
             float* __restrict__ Cpart, int M, int N, int K) {
    __shared__ __align__(16) us S[2][4][64 * 32];
    const int tid = threadIdx.x, wave = tid >> 6, lane = tid & 63;
    const int quad = lane >> 4, l15 = lane & 15;
    const int wm = wave & 1, wn = wave >> 1;
    const int m0 = blockIdx.y * 64, n0 = blockIdx.x * 64;
    const int Ks = K / gridDim.z, kbeg = blockIdx.z * Ks, kend = kbeg + Ks;
    float* C = Cpart + (size_t)blockIdx.z * M * N;

    const int srow = wave * 16 + (lane >> 2), soff = (lane & 3) * 8;
    const size_t gaB = (size_t)(m0 + srow) * K + soff;
    const size_t gbB = (size_t)(n0 + srow) * K + soff;
    const int lo = wave * 16 * 32;

    f32x4 acc[2][2];
#pragma unroll
    for (int a = 0; a < 2; ++a)
#pragma unroll
        for (int b = 0; b < 2; ++b) acc[a][b] = (f32x4){0.f, 0.f, 0.f, 0.f};

    auto stage = [&](int p, int k0) {
        gload16(Ah + gaB + k0, &S[p][0][lo]);
        gload16(Al + gaB + k0, &S[p][1][lo]);
        gload16(BhT + gbB + k0, &S[p][2][lo]);
        gload16(BlT + gbB + k0, &S[p][3][lo]);
    };

    int p = 0;
    stage(0, kbeg);
    for (int k0 = kbeg; k0 < kend; k0 += 32) {
        __syncthreads();
        if (k0 + 32 < kend) stage(p ^ 1, k0 + 32);
        short8 ah[2], al[2], bh[2], bl[2];
#pragma unroll
        for (int mt = 0; mt < 2; ++mt) {
            int off = (wm * 32 + mt * 16 + l15) * 32 + quad * 8;
            ah[mt] = *(const short8*)&S[p][0][off];
            al[mt] = *(const short8*)&S[p][1][off];
        }
#pragma unroll
        for (int nt = 0; nt < 2; ++nt) {
            int off = (wn * 32 + nt * 16 + l15) * 32 + quad * 8;
            bh[nt] = *(const short8*)&S[p][2][off];
            bl[nt] = *(const short8*)&S[p][3][off];
        }
#pragma unroll
        for (int mt = 0; mt < 2; ++mt)
#pragma unroll
            for (int nt = 0; nt < 2; ++nt) {
                acc[mt][nt] = __builtin_amdgcn_mfma_f32_16x16x32_bf16(al[mt], bh[nt], acc[mt][nt], 0, 0, 0);
                acc[mt][nt] = __builtin_amdgcn_mfma_f32_16x16x32_bf16(ah[mt], bl[nt], acc[mt][nt], 0, 0, 0);
                acc[mt][nt] = __builtin_amdgcn_mfma_f32_16x16x32_bf16(ah[mt], bh[nt], acc[mt][nt], 0, 0, 0);
            }
        p ^= 1;
    }
#pragma unroll
    for (int mt = 0; mt < 2; ++mt)
#pragma unroll
        for (int nt = 0; nt < 2; ++nt) {
            int col = n0 + wn * 32 + nt * 16 + l15;
#pragma unroll
            for (int reg = 0; reg < 4; ++reg) {
                int row = m0 + wm * 32 + mt * 16 + quad * 4 + reg;
                C[(size_t)row * N + col] = acc[mt][nt][reg];
            }
        }
}

// ---------- split-bf16 GEMM, z=1, fused outputs (bias + f32 / hi-lo split / 16-bit) ----------
__global__ __launch_bounds__(256)
void k_gemm3(const us* __restrict__ Ah, const us* __restrict__ Al,
             const us* __restrict__ BhT, const us* __restrict__ BlT,
             const float* __restrict__ bias, float* __restrict__ outF,
             us* __restrict__ sh, us* __restrict__ sl, us* __restrict__ bh16,
             int fp16out, int scols, int N, int K) {
    __shared__ __align__(16) us S[2][4][64 * 32];
    const int tid = threadIdx.x, wave = tid >> 6, lane = tid & 63;
    const int quad = lane >> 4, l15 = lane & 15;
    const int wm = wave & 1, wn = wave >> 1;
    const int m0 = blockIdx.y * 64, n0 = blockIdx.x * 64;

    const int srow = wave * 16 + (lane >> 2), soff = (lane & 3) * 8;
    const size_t gaB = (size_t)(m0 + srow) * K + soff;
    const size_t gbB = (size_t)(n0 + srow) * K + soff;
    const int lo = wave * 16 * 32;

    f32x4 acc[2][2];
#pragma unroll
    for (int a = 0; a < 2; ++a)
#pragma unroll
        for (int b = 0; b < 2; ++b) acc[a][b] = (f32x4){0.f, 0.f, 0.f, 0.f};

    auto stage = [&](int p, int k0) {
        gload16(Ah + gaB + k0, &S[p][0][lo]);
        gload16(Al + gaB + k0, &S[p][1][lo]);
        gload16(BhT + gbB + k0, &S[p][2][lo]);
        gload16(BlT + gbB + k0, &S[p][3][lo]);
    };

    int p = 0;
    stage(0, 0);
    for (int k0 = 0; k0 < K; k0 += 32) {
        __syncthreads();
        if (k0 + 32 < K) stage(p ^ 1, k0 + 32);
        short8 ah[2], al[2], bh[2], bl[2];
#pragma unroll
        for (int mt = 0; mt < 2; ++mt) {
            int off = (wm * 32 + mt * 16 + l15) * 32 + quad * 8;
            ah[mt] = *(const short8*)&S[p][0][off];
            al[mt] = *(const short8*)&S[p][1][off];
        }
#pragma unroll
        for (int nt = 0; nt < 2; ++nt) {
            int off = (wn * 32 + nt * 16 + l15) * 32 + quad * 8;
            bh[nt] = *(const short8*)&S[p][2][off];
            bl[nt] = *(const short8*)&S[p][3][off];
        }
#pragma unroll
        for (int mt = 0; mt < 2; ++mt)
#pragma unroll
            for (int nt = 0; nt < 2; ++nt) {
                acc[mt][nt] = __builtin_amdgcn_mfma_f32_16x16x32_bf16(al[mt], bh[nt], acc[mt][nt], 0, 0, 0);
                acc[mt][nt] = __builtin_amdgcn_mfma_f32_16x16x32_bf16(ah[mt], bl[nt], acc[mt][nt], 0, 0, 0);
                acc[mt][nt] = __builtin_amdgcn_mfma_f32_16x16x32_bf16(ah[mt], bh[nt], acc[mt][nt], 0, 0, 0);
            }
        p ^= 1;
    }
#pragma unroll
    for (int mt = 0; mt < 2; ++mt)
#pragma unroll
        for (int nt = 0; nt < 2; ++nt) {
            int col = n0 + wn * 32 + nt * 16 + l15;
            float bb = bias ? bias[col] : 0.f;
#pragma unroll
            for (int reg = 0; reg < 4; ++reg) {
                int row = m0 + wm * 32 + mt * 16 + quad * 4 + reg;
                float v = acc[mt][nt][reg] + bb;
                if (outF) outF[(size_t)row * N + col] = v;
                if (sh) {
                    if (col < scols) {
                        us h, l;
                        split1(v, h, l);
                        size_t o = (size_t)row * scols + col;
                        sh[o] = h;
                        sl[o] = l;
                    } else if (bh16) {
                        bh16[(size_t)row * scols + (col - scols)] = fp16out ? f2h(v) : f2b(v);
                    }
                }
            }
        }
}

// ---------- reduce partials + bias; f32 out + hi/lo split (col<scols) + 16-bit (col>=scols) ----------
__global__ __launch_bounds__(256)
void k_reduce(const float* __restrict__ part, int S, int MN, int N,
              const float* __restrict__ bias, float* __restrict__ outF,
              us* __restrict__ sh, us* __restrict__ sl, int scols,
              us* __restrict__ bh16, int fp16out) {
    int i = blockIdx.x * 256 + threadIdx.x;
    if (i >= MN) return;
    float v = 0.f;
    for (int s = 0; s < S; ++s) v += part[(size_t)s * MN + i];
    int row = i / N, col = i - row * N;
    if (bias) v += bias[col];
    if (outF) outF[i] = v;
    if (col < scols) {
        if (sh) {
            us h, l;
            split1(v, h, l);
            size_t o = (size_t)row * scols + col;
            sh[o] = h;
            sl[o] = l;
        }
    } else if (bh16) {
        bh16[(size_t)row * scols + (col - scols)] = fp16out ? f2h(v) : f2b(v);
    }
}

// ---------------- P-GEMM v15: v13 (256x256 8-phase template) with LEAN epilogue ----------------
// R7 post-mortem: v13's spill (FETCH 92MB) was caused by the epilogue preloading
// w2v[4][4][3]+bcv (~112 extra live regs on top of acc 128), NOT by the schedule.
// v14 (spill-free but 8-MFMA phases) regressed -> template needs the BIG per-wave tile.
// v15 = v13's exact geometry+schedule, epilogue restructured to inline loads
// (nf-outer/mf-inner, Aw/Bc/W2 re-read from L1/L2 per nf) -> epilogue live set ~25 regs.
// K-loop live: acc 128 + frags 16 + addr ~40 = ~190 < 256. Pre-committed: if spill
// (FETCH >> 8MB) or dur >= 118us, revert to v10 permanently.
__global__ __launch_bounds__(512, 1)
void k_mfma15(const us* __restrict__ t1b,   // (1024,768) fp16   (B side, n=w)
              const us* __restrict__ W1ct,  // (768,768) fp16 [j][k]  (A side, m=j)
              const us* __restrict__ lb1b,  // (64,768) fp16
              const float* __restrict__ Aw, // (1024,768) f32
              const float* __restrict__ Bc, // (64,768) f32 (includes b1)
              const float* __restrict__ W2, // (768,3) f32
              float* __restrict__ scr) {    // (3,1024,64,3) f32 partials
    __shared__ __align__(16) us RA[3][8192];   // slot: [q=4][row=256][8] fp16, 16 KB
    __shared__ __align__(16) us RB[3][8192];
    __shared__ __align__(16) us lbs[Hd];       // lb1 row c (1.5 KB)
    __shared__ float sred[256 * 3];

    const int tid = threadIdx.x, wave = tid >> 6, lane = tid & 63;
    const int quad = lane >> 4, l15 = lane & 15;
    const int wm2 = wave >> 2, wn4 = wave & 3;   // 2 x 4 wave grid (m=j, n=w)

    // decode: 768 blocks = 8 xcd * 96; per xcd: 12 (jb,wb) tiles x 8 consecutive c
    const int b = blockIdx.x;
    const int xcd = b & 7, s5 = b >> 3;        // s5 0..95
    const int cl = s5 & 7, idx = s5 >> 3;      // idx 0..11
    const int jb = idx % 3, wb = idx / 3;      // jb 0..2 (j tile), wb 0..3 (w tile)
    const int c  = xcd * 8 + cl;

    for (int i = tid; i < 256 * 3; i += 512) sred[i] = 0.f;
    if (tid < 96) *(short8*)&lbs[tid * 8] = *(const short8*)&lb1b[(size_t)c * Hd + tid * 8];

    // staging map: wave issues per step 2 A-insts + 2 B-insts (1 KB each):
    //   inst (q = wave&3, r64 = (wave>>2)*2 + j), lane -> row r64*64+lane
    const int q = wave & 3, rh = wave >> 2;
    const us* gA0 = W1ct + (size_t)(jb * 256 + (rh * 2 + 0) * 64 + lane) * Hd + q * 8;
    const us* gA1 = W1ct + (size_t)(jb * 256 + (rh * 2 + 1) * 64 + lane) * Hd + q * 8;
    const us* gB0 = t1b + (size_t)(wb * 256 + (rh * 2 + 0) * 64 + lane) * Hd + q * 8;
    const us* gB1 = t1b + (size_t)(wb * 256 + (rh * 2 + 1) * 64 + lane) * Hd + q * 8;
    const int dA0 = q * 2048 + (rh * 2 + 0) * 512;   // us offsets
    const int dA1 = q * 2048 + (rh * 2 + 1) * 512;

    f32x4 acc[8][4];
#pragma unroll
    for (int mf = 0; mf < 8; ++mf)
#pragma unroll
        for (int nf = 0; nf < 4; ++nf) acc[mf][nf] = (f32x4){0.f, 0.f, 0.f, 0.f};

    auto stagePh = [&](int slot, int k0, int j) {
        if (j == 0) { gload16(gA0 + k0, &RA[slot][dA0]); gload16(gB0 + k0, &RB[slot][dA0]); }
        else        { gload16(gA1 + k0, &RA[slot][dA1]); gload16(gB1 + k0, &RB[slot][dA1]); }
    };

    // fragment read bases (us): elem (q=quad, row) at quad*2048 + row*8
    const int rbA = quad * 2048 + (wm2 * 128 + l15) * 8;   // + mf*128
    const int rbB = quad * 2048 + (wn4 * 64 + l15) * 8;    // + nf*128

    __syncthreads();   // lbs/sred visible; VMEM queue drained -> vmcnt counting starts clean

    stagePh(0, 0, 0);  stagePh(0, 0, 1);     // step 0
    stagePh(1, 32, 0); stagePh(1, 32, 1);    // step 1  (8 loads in flight)

#pragma unroll
    for (int s = 0; s < 24; ++s) {
        const int slot = s % 3;
        if (s < 23) asm volatile("s_waitcnt vmcnt(4)" ::: "memory");  // step-s loads landed
        else        asm volatile("s_waitcnt vmcnt(0)" ::: "memory");
        __builtin_amdgcn_s_barrier();
        __builtin_amdgcn_sched_barrier(0);
        // ---- phase A: mf 0-3 ----
        short8 bF[4], aF[4];
        short8 lv = *(const short8*)&lbs[s * 32 + quad * 8];
#pragma unroll
        for (int nf = 0; nf < 4; ++nf) bF[nf] = *(const short8*)&RB[slot][rbB + nf * 128];
#pragma unroll
        for (int i = 0; i < 4; ++i) aF[i] = *(const short8*)&RA[slot][rbA + i * 128];
        if (s + 2 < 24) stagePh((s + 2) % 3, (s + 2) * 32, 0);
        asm volatile("s_waitcnt lgkmcnt(0)" ::: "memory");
        __builtin_amdgcn_sched_barrier(0);
        __builtin_amdgcn_s_setprio(1);
#pragma unroll
        for (int i = 0; i < 4; ++i) {
            short8 aS = hmul8(aF[i], lv);
#pragma unroll
            for (int nf = 0; nf < 4; ++nf)
                acc[i][nf] = __builtin_amdgcn_mfma_f32_16x16x32_f16(
                    __builtin_bit_cast(half8, aS),
                    __builtin_bit_cast(half8, bF[nf]), acc[i][nf], 0, 0, 0);
        }
        __builtin_amdgcn_s_setprio(0);
        __builtin_amdgcn_s_barrier();
        // ---- phase B: mf 4-7 ----
#pragma unroll
        for (int i = 0; i < 4; ++i) aF[i] = *(const short8*)&RA[slot][rbA + (4 + i) * 128];
        if (s + 2 < 24) stagePh((s + 2) % 3, (s + 2) * 32, 1);
        asm volatile("s_waitcnt lgkmcnt(0)" ::: "memory");
        __builtin_amdgcn_sched_barrier(0);
        __builtin_amdgcn_s_setprio(1);
#pragma unroll
        for (int i = 0; i < 4; ++i) {
            short8 aS = hmul8(aF[i], lv);
#pragma unroll
            for (int nf = 0; nf < 4; ++nf)
                acc[4 + i][nf] = __builtin_amdgcn_mfma_f32_16x16x32_f16(
                    __builtin_bit_cast(half8, aS),
                    __builtin_bit_cast(half8, bF[nf]), acc[4 + i][nf], 0, 0, 0);
        }
        __builtin_amdgcn_s_setprio(0);
    }

    // ---- LEAN epilogue: h = relu(P + Aw[w,j] + Bc[c,j]); s[w][r] += h*W2[j,r] ----
    // nf-outer / mf-inner; Aw/Bc/W2 loaded inline (L1/L2-hot), no preload arrays.
    // j = jb*256 + wm2*128 + mf*16 + quad*4 + reg ; w = wb*256 + wn4*64 + nf*16 + l15
#pragma unroll
    for (int nf = 0; nf < 4; ++nf) {
        const int w = wb * 256 + wn4 * 64 + nf * 16 + l15;
        float s0 = 0.f, s1 = 0.f, s2 = 0.f;
#pragma unroll
        for (int mf = 0; mf < 8; ++mf) {
            const int jg = jb * 256 + wm2 * 128 + mf * 16 + quad * 4;
            float4 a4 = *(const float4*)&Aw[(size_t)w * Hd + jg];
            float4 bc4 = *(const float4*)&Bc[(size_t)c * Hd + jg];
            float av[4] = {a4.x, a4.y, a4.z, a4.w};
            float bv[4] = {bc4.x, bc4.y, bc4.z, bc4.w};
#pragma unroll
            for (int reg = 0; reg < 4; ++reg) {
                float h = acc[mf][nf][reg] + av[reg] + bv[reg];
                h = h > 0.f ? h : 0.f;
                s0 += h * W2[(jg + reg) * 3 + 0];
                s1 += h * W2[(jg + reg) * 3 + 1];
                s2 += h * W2[(jg + reg) * 3 + 2];
            }
        }
        s0 += __shfl_xor(s0, 16); s0 += __shfl_xor(s0, 32);
        s1 += __shfl_xor(s1, 16); s1 += __shfl_xor(s1, 32);
        s2 += __shfl_xor(s2, 16); s2 += __shfl_xor(s2, 32);
        if (quad == 0) {
            const int wl = wn4 * 64 + nf * 16 + l15;
            atomicAdd(&sred[wl * 3 + 0], s0);   // 2-way contention (wm2)
            atomicAdd(&sred[wl * 3 + 1], s1);
            atomicAdd(&sred[wl * 3 + 2], s2);
        }
    }
    __syncthreads();

    // store to per-jb scratch slab (disjoint across blocks)
    float* slab = scr + (size_t)jb * (1024 * Cn * 3);
    for (int i = tid; i < 256 * 3; i += 512) {
        int wl = i / 3, r = i - wl * 3;
        slab[((size_t)(wb * 256 + wl) * Cn + c) * 3 + r] = sred[i];
    }
}

// ---------- final: out = b2 + sum_jb scr[jb] ----------
__global__ __launch_bounds__(256)
void k_scores(const float* __restrict__ scr, const float* __restrict__ b2,
              float* __restrict__ out, int n) {
    int i = blockIdx.x * 256 + threadIdx.x;
    if (i >= n) return;
    float v = b2[i % 3];
#pragma unroll
    for (int s = 0; s < 3; ++s) v += scr[(size_t)s * n + i];
    out[i] = v;
}

extern "C" void kernel_launch(void* const* d_in, const int* in_sizes, int n_in,
                              void* d_out, int out_size, void* d_ws, size_t ws_size,
                              hipStream_t stream) {
    const float* tok    = (const float*)d_in[0];
    const int*   wmask  = (const int*)d_in[1];
    const float* labe   = (const float*)d_in[3];
    const float* W_tok  = (const float*)d_in[4];
    const float* b_tok  = (const float*)d_in[5];
    const float* W_lab  = (const float*)d_in[6];
    const float* b_lab  = (const float*)d_in[7];
    const float* W1     = (const float*)d_in[8];
    const float* b1     = (const float*)d_in[9];
    const float* W2     = (const float*)d_in[10];
    const float* b2     = (const float*)d_in[11];
    float* out = (float*)d_out;

    const int L  = in_sizes[1];
    const int Wd = out_size / (Cn * 3);   // 1024

    char* ws = (char*)d_ws;
    size_t off = 0;
    auto alloc = [&](size_t bytes) { char* p = ws + off; off += (bytes + 255) & ~(size_t)255; return p; };
    // ---- persistent region ----
    int*   widx  = (int*)alloc(4096);
    float* Abuf  = (float*)alloc((size_t)Wd * Hd * 4);
    float* Bbuf  = (float*)alloc((size_t)Cn * Hd * 4);
    us* W1ct  = (us*)alloc((size_t)Hd * Hd * 2);   // fp16
    us* W1cl  = (us*)alloc((size_t)Hd * Hd * 2);   // unused
    us* t1b   = (us*)alloc((size_t)Wd * Hd * 2);   // fp16
    us* lb1b  = (us*)alloc((size_t)Cn * Hd * 2);   // fp16
    float* scr = (float*)alloc((size_t)3 * Wd * Cn * 3 * 4);   // 2.36 MB partials
    // ---- scratch region ----
    us* WtTh  = (us*)alloc((size_t)H2 * Hd * 2);
    us* WtTl  = (us*)alloc((size_t)H2 * Hd * 2);
    us* WlTh  = (us*)alloc((size_t)H2 * Hd * 2);
    us* WlTl  = (us*)alloc((size_t)H2 * Hd * 2);
    us* W1aTh = (us*)alloc((size_t)Hd * Hd * 2);
    us* W1aTl = (us*)alloc((size_t)Hd * Hd * 2);
    us* W1bTh = (us*)alloc((size_t)Hd * Hd * 2);
    us* W1bTl = (us*)alloc((size_t)Hd * Hd * 2);
    us* weh   = (us*)alloc((size_t)Wd * Hd * 2);
    us* wel   = (us*)alloc((size_t)Wd * Hd * 2);
    us* lah   = (us*)alloc((size_t)Cn * Hd * 2);
    us* lal   = (us*)alloc((size_t)Cn * Hd * 2);
    us* t0h   = (us*)alloc((size_t)Wd * Hd * 2);
    us* t0l   = (us*)alloc((size_t)Wd * Hd * 2);
    us* lb0h  = (us*)alloc((size_t)Cn * Hd * 2);
    us* lb0l  = (us*)alloc((size_t)Cn * Hd * 2);
    float* part = (float*)alloc((size_t)8 * Cn * H2 * 4);

    // 1) init + scatter + we split
    k_init<<<(Wd + 255) / 256, 256, 0, stream>>>(widx, Wd);
    k_scatter<<<(L + 255) / 256, 256, 0, stream>>>(wmask, widx, L, Wd);
    k_build_we_split<<<(Wd * 192 + 255) / 256, 256, 0, stream>>>((const float4*)tok, widx, weh, wel, Wd);

    // 2) batched weight transpose+split (W1c -> fp16)
    TSArgs ts;
    ts.src[0] = W_tok;  ts.th[0] = WtTh;  ts.tl[0] = WtTl;  ts.ld[0] = H2; ts.N[0] = H2; ts.fmt[0] = 0;
    ts.src[1] = W_lab;  ts.th[1] = WlTh;  ts.tl[1] = WlTl;  ts.ld[1] = H2; ts.N[1] = H2; ts.fmt[1] = 0;
    ts.src[2] = W1;                         ts.th[2] = W1aTh; ts.tl[2] = W1aTl; ts.ld[2] = Hd; ts.N[2] = Hd; ts.fmt[2] = 0;
    ts.src[3] = W1 + (size_t)Hd * Hd;       ts.th[3] = W1bTh; ts.tl[3] = W1bTl; ts.ld[3] = Hd; ts.N[3] = Hd; ts.fmt[3] = 0;
    ts.src[4] = W1 + (size_t)2 * Hd * Hd;   ts.th[4] = W1ct;  ts.tl[4] = W1cl;  ts.ld[4] = Hd; ts.N[4] = Hd; ts.fmt[4] = 1;
    k_tsplit<<<dim3(H2 / 64, Hd / 64, 5), 256, 0, stream>>>(ts);

    // 3) label emb split
    k_split<<<(Cn * Hd / 4 + 255) / 256, 256, 0, stream>>>(labe, Hd, Hd, lah, lal, Cn * Hd / 4);

    // 4) t = we @ W_tok + b_tok -> fused t0 hi/lo + t1b fp16
    k_gemm3<<<dim3(H2 / 64, Wd / 64), 256, 0, stream>>>(weh, wel, WtTh, WtTl, b_tok,
                                                        nullptr, t0h, t0l, t1b, 1, Hd, H2, Hd);

    // 5) lb = labe @ W_lab + b_lab (64x1536), z=8 -> reduce (lb0 split + lb1b fp16)
    k_gemm2<<<dim3(H2 / 64, 1, 8), 256, 0, stream>>>(lah, lal, WlTh, WlTl, part, Cn, H2, Hd);
    k_reduce<<<(Cn * H2 + 255) / 256, 256, 0, stream>>>(part, 8, Cn * H2, H2, b_lab, nullptr, lb0h, lb0l, Hd, lb1b, 1);

    // 6) Aw = t0 @ W1a (1024x768) -> fused f32 write
    k_gemm3<<<dim3(Hd / 64, Wd / 64), 256, 0, stream>>>(t0h, t0l, W1aTh, W1aTl, nullptr,
                                                        Abuf, nullptr, nullptr, nullptr, 0, 0, Hd, Hd);

    // 7) Bc = lb0 @ W1b + b1 (64x768), z=8 -> reduce
    k_gemm2<<<dim3(Hd / 64, 1, 8), 256, 0, stream>>>(lb0h, lb0l, W1bTh, W1bTl, part, Cn, Hd, Hd);
    k_reduce<<<(Cn * Hd + 255) / 256, 256, 0, stream>>>(part, 8, Cn * Hd, Hd, b1, Bbuf, nullptr, nullptr, Hd, nullptr, 0);

    // 8) fused fp16 P-GEMM v15 (256x256 template, lean epilogue) -> scratch
    k_mfma15<<<768, 512, 0, stream>>>(t1b, W1ct, lb1b, Abuf, Bbuf, W2, scr);

    // 9) out = b2 + sum_jb scr
    k_scores<<<(Wd * Cn * 3 + 255) / 256, 256, 0, stream>>>(scr, b2, out, Wd * Cn * 3);
}

// Round 10
// 260.197 us; speedup vs baseline: 1.4605x; 1.1054x over previous
//
#include <hip/hip_runtime.h>
#include <hip/hip_bf16.h>

static constexpr int Hd = 768;    // H
static constexpr int H2 = 1536;   // 2H
static constexpr int Cn = 64;     // C (labels)

typedef __attribute__((ext_vector_type(8))) short short8;
typedef __attribute__((ext_vector_type(8))) _Float16 half8;
typedef __attribute__((ext_vector_type(4))) float f32x4;
typedef unsigned short us;

__device__ inline void split1(float x, us& h, us& l) {
    __hip_bfloat16 hb = __float2bfloat16(x);
    float hf = __bfloat162float(hb);
    __hip_bfloat16 lb_ = __float2bfloat16(x - hf);
    h = *reinterpret_cast<us*>(&hb);
    l = *reinterpret_cast<us*>(&lb_);
}

__device__ inline us f2b(float x) {
    __hip_bfloat16 b = __float2bfloat16(x);
    return *reinterpret_cast<us*>(&b);
}

__device__ inline us f2h(float x) {
    _Float16 h = (_Float16)x;
    return *reinterpret_cast<us*>(&h);
}

// packed fp16 elementwise product: 4x v_pk_mul_f16
__device__ inline short8 hmul8(short8 a, short8 b) {
    half8 x = __builtin_bit_cast(half8, a);
    half8 y = __builtin_bit_cast(half8, b);
    half8 r = x * y;
    return __builtin_bit_cast(short8, r);
}

__device__ inline void gload16(const void* g, void* l) {
    __builtin_amdgcn_global_load_lds(
        (const __attribute__((address_space(1))) unsigned int*)g,
        (__attribute__((address_space(3))) unsigned int*)l, 16, 0, 0);
}

// ---------------- init: widx = -1 (kernel, NOT hipMemsetAsync — graph-capture safe) ----------------
__global__ void k_init(int* widx, int Wd) {
    int i = blockIdx.x * 256 + threadIdx.x;
    if (i < Wd) widx[i] = -1;
}

__global__ void k_scatter(const int* __restrict__ wmask, int* widx, int L, int Wd) {
    int i = blockIdx.x * 256 + threadIdx.x;
    if (i < L) {
        int m = wmask[i];
        if (m > 0 && m <= Wd) atomicMax(&widx[m - 1], i);  // last token wins
    }
}

// build we (scatter-pooled tok rows) as hi/lo bf16 split, AND labe split (merged kernel)
__global__ void k_build_we_labe(const float4* __restrict__ tok, const int* __restrict__ widx,
                                us* __restrict__ weh, us* __restrict__ wel, int Wd,
                                const float4* __restrict__ labe,
                                us* __restrict__ lah, us* __restrict__ lal) {
    int gi = blockIdx.x * 256 + threadIdx.x;
    const int nwe = Wd * 192;                 // we range (float4 granularity)
    float4 v;
    size_t o;
    us hh[4], ll[4];
    if (gi < nwe) {
        int w = gi / 192, c4 = gi - w * 192;
        int idx = widx[w];
        v = (idx >= 0) ? tok[idx * 192 + c4] : float4{0.f, 0.f, 0.f, 0.f};
        o = (size_t)w * Hd + c4 * 4;
        split1(v.x, hh[0], ll[0]);
        split1(v.y, hh[1], ll[1]);
        split1(v.z, hh[2], ll[2]);
        split1(v.w, hh[3], ll[3]);
        *(ushort4*)&weh[o] = ushort4{hh[0], hh[1], hh[2], hh[3]};
        *(ushort4*)&wel[o] = ushort4{ll[0], ll[1], ll[2], ll[3]};
    } else {
        int i = gi - nwe;                     // labe range: Cn*192 float4s
        if (i >= Cn * 192) return;
        v = labe[i];
        o = (size_t)i * 4;
        split1(v.x, hh[0], ll[0]);
        split1(v.y, hh[1], ll[1]);
        split1(v.z, hh[2], ll[2]);
        split1(v.w, hh[3], ll[3]);
        *(ushort4*)&lah[o] = ushort4{hh[0], hh[1], hh[2], hh[3]};
        *(ushort4*)&lal[o] = ushort4{ll[0], ll[1], ll[2], ll[3]};
    }
}

// ---------- batched transpose + split: T[n][k]; fmt=0 bf16 hi/lo, fmt=1 fp16 (Th only) ----------
struct TSArgs {
    const float* src[5];
    us* th[5];
    us* tl[5];
    int ld[5];
    int N[5];
    int fmt[5];
};
__global__ __launch_bounds__(256)
void k_tsplit(TSArgs a) {
    __shared__ float tile[64][65];
    const int z = blockIdx.z;
    const int n0 = blockIdx.x * 64, k0 = blockIdx.y * 64;
    if (n0 >= a.N[z]) return;
    const float* W = a.src[z];
    const int ld = a.ld[z];
    for (int idx = threadIdx.x; idx < 4096; idx += 256) {
        int kk = idx >> 6, nn = idx & 63;
        tile[kk][nn] = W[(size_t)(k0 + kk) * ld + n0 + nn];
    }
    __syncthreads();
    us* Th = a.th[z];
    us* Tl = a.tl[z];
    const int fmt = a.fmt[z];
    for (int idx = threadIdx.x; idx < 4096; idx += 256) {
        int nn = idx >> 6, kk = idx & 63;
        size_t o = (size_t)(n0 + nn) * Hd + k0 + kk;
        if (fmt) {
            Th[o] = f2h(tile[kk][nn]);
        } else {
            us h, l;
            split1(tile[kk][nn], h, l);
            Th[o] = h;
            Tl[o] = l;
        }
    }
}

// ---------- split-bf16 GEMM, z=1, fused outputs (bias + f32 / hi-lo split / 16-bit) ----------
__global__ __launch_bounds__(256)
void k_gemm3(const us* __restrict__ Ah, const us* __restrict__ Al,
             const us* __restrict__ BhT, const us* __restrict__ BlT,
             const float* __restrict__ bias, float* __restrict__ outF,
             us* __restrict__ sh, us* __restrict__ sl, us* __restrict__ bh16,
             int fp16out, int scols, int N, int K) {
    __shared__ __align__(16) us S[2][4][64 * 32];
    const int tid = threadIdx.x, wave = tid >> 6, lane = tid & 63;
    const int quad = lane >> 4, l15 = lane & 15;
    const int wm = wave & 1, wn = wave >> 1;
    const int m0 = blockIdx.y * 64, n0 = blockIdx.x * 64;

    const int srow = wave * 16 + (lane >> 2), soff = (lane & 3) * 8;
    const size_t gaB = (size_t)(m0 + srow) * K + soff;
    const size_t gbB = (size_t)(n0 + srow) * K + soff;
    const int lo = wave * 16 * 32;

    f32x4 acc[2][2];
#pragma unroll
    for (int a = 0; a < 2; ++a)
#pragma unroll
        for (int b = 0; b < 2; ++b) acc[a][b] = (f32x4){0.f, 0.f, 0.f, 0.f};

    auto stage = [&](int p, int k0) {
        gload16(Ah + gaB + k0, &S[p][0][lo]);
        gload16(Al + gaB + k0, &S[p][1][lo]);
        gload16(BhT + gbB + k0, &S[p][2][lo]);
        gload16(BlT + gbB + k0, &S[p][3][lo]);
    };

    int p = 0;
    stage(0, 0);
    for (int k0 = 0; k0 < K; k0 += 32) {
        __syncthreads();
        if (k0 + 32 < K) stage(p ^ 1, k0 + 32);
        short8 ah[2], al[2], bh[2], bl[2];
#pragma unroll
        for (int mt = 0; mt < 2; ++mt) {
            int off = (wm * 32 + mt * 16 + l15) * 32 + quad * 8;
            ah[mt] = *(const short8*)&S[p][0][off];
            al[mt] = *(const short8*)&S[p][1][off];
        }
#pragma unroll
        for (int nt = 0; nt < 2; ++nt) {
            int off = (wn * 32 + nt * 16 + l15) * 32 + quad * 8;
            bh[nt] = *(const short8*)&S[p][2][off];
            bl[nt] = *(const short8*)&S[p][3][off];
        }
#pragma unroll
        for (int mt = 0; mt < 2; ++mt)
#pragma unroll
            for (int nt = 0; nt < 2; ++nt) {
                acc[mt][nt] = __builtin_amdgcn_mfma_f32_16x16x32_bf16(al[mt], bh[nt], acc[mt][nt], 0, 0, 0);
                acc[mt][nt] = __builtin_amdgcn_mfma_f32_16x16x32_bf16(ah[mt], bl[nt], acc[mt][nt], 0, 0, 0);
                acc[mt][nt] = __builtin_amdgcn_mfma_f32_16x16x32_bf16(ah[mt], bh[nt], acc[mt][nt], 0, 0, 0);
            }
        p ^= 1;
    }
#pragma unroll
    for (int mt = 0; mt < 2; ++mt)
#pragma unroll
        for (int nt = 0; nt < 2; ++nt) {
            int col = n0 + wn * 32 + nt * 16 + l15;
            float bb = bias ? bias[col] : 0.f;
#pragma unroll
            for (int reg = 0; reg < 4; ++reg) {
                int row = m0 + wm * 32 + mt * 16 + quad * 4 + reg;
                float v = acc[mt][nt][reg] + bb;
                if (outF) outF[(size_t)row * N + col] = v;
                if (sh) {
                    if (col < scols) {
                        us h, l;
                        split1(v, h, l);
                        size_t o = (size_t)row * scols + col;
                        sh[o] = h;
                        sl[o] = l;
                    } else if (bh16) {
                        bh16[(size_t)row * scols + (col - scols)] = fp16out ? f2h(v) : f2b(v);
                    }
                }
            }
        }
}

// ---------------- P-GEMM v10 (FINAL): reg double-buffered fragments, 2-label tiles ----------------
// Session verdict (R1-R8): v10's 655 TF effective (27% MfmaUtil) is this op's structural
// plateau. Falsified alternatives: counted-vmcnt alone (v9, NULL), 3-wave occupancy
// reshape (v11, -27%), barrier-free private slices (v12, -119%), 256^2 8-phase template
// (v13 spilled; v15 clean test -31%), small-tile fine phases (v14, -42%).
__global__ __launch_bounds__(256, 2)
void k_mfma10(const us* __restrict__ t1b,   // (1024,768) fp16
              const us* __restrict__ W1ct,  // (768,768) fp16 [j][k]
              const us* __restrict__ lb1b,  // (64,768) fp16
              const float* __restrict__ Aw, // (1024,768) f32
              const float* __restrict__ Bc, // (64,768) f32 (includes b1)
              const float* __restrict__ W2, // (768,3) f32
              float* __restrict__ scr) {    // (6,1024,64,3) f32 partials
    __shared__ __align__(16) us As[3][4096];   // [q][row][8] chunk-major, 8 KB per buf
    __shared__ __align__(16) us Bs[3][4096];
    __shared__ __align__(16) us lbs[2][Hd];    // lb1 rows for the 2 labels
    __shared__ float sred[2 * 128 * 3];

    const int tid = threadIdx.x, wave = tid >> 6, lane = tid & 63;
    const int quad = lane >> 4, l15 = lane & 15;
    const int wm = wave & 1, wn = wave >> 1;

    // L2-locality decode: b = xcd + 8*(jx*32 + cp); my = xcd
    const int b = blockIdx.x;
    const int xcd = b & 7, slot = b >> 3;    // slot 0..191
    const int jx = slot >> 5;                // 0..5
    const int cp = slot & 31;                // 0..31 (varies fastest)
    const int c0 = cp * 2;
    const int jt = jx * 128, m0 = xcd * 128;

    for (int i = tid; i < 2 * 128 * 3; i += 256) sred[i] = 0.f;
    if (tid < 192) {                          // stage lb1 rows c0,c0+1 (3 KB)
        int cc = tid / 96, o = (tid - cc * 96) * 8;
        *(short8*)&lbs[cc][o] = *(const short8*)&lb1b[(size_t)(c0 + cc) * Hd + o];
    }

    // staging map: wave issues chunks i=wave and i=wave+4; i -> (q=i>>1, rhalf=i&1)
    const int srow = (wave & 1) * 64 + lane;
    const int skq = (wave >> 1) * 8;          // k offset of chunk q within the 32-k step
    const us* gA = W1ct + (size_t)(jt + srow) * Hd + skq;
    const us* gB = t1b + (size_t)(m0 + srow) * Hd + skq;

    f32x4 acc0[4][4], acc1[4][4];
#pragma unroll
    for (int mt = 0; mt < 4; ++mt)
#pragma unroll
        for (int nt = 0; nt < 4; ++nt) {
            acc0[mt][nt] = (f32x4){0.f, 0.f, 0.f, 0.f};
            acc1[mt][nt] = (f32x4){0.f, 0.f, 0.f, 0.f};
        }

    auto stageT = [&](int p, int k0) {
        gload16(gA + k0,      &As[p][wave * 512]);
        gload16(gA + k0 + 16, &As[p][(wave + 4) * 512]);
        gload16(gB + k0,      &Bs[p][wave * 512]);
        gload16(gB + k0 + 16, &Bs[p][(wave + 4) * 512]);
    };

    // fragment read bases: element (q, row) at us-index q*1024 + row*8
    const int rbA = quad * 1024 + (wm * 64 + l15) * 8;
    const int rbB = quad * 1024 + (wn * 64 + l15) * 8;

    auto readFrags = [&](short8 (&af)[4], short8 (&bf)[4], short8& l0, short8& l1,
                         int buf, int k0) {
        const us* Ab = &As[buf][0];
        const us* Bb = &Bs[buf][0];
#pragma unroll
        for (int mt = 0; mt < 4; ++mt) af[mt] = *(const short8*)&Ab[rbA + mt * 128];
#pragma unroll
        for (int nt = 0; nt < 4; ++nt) bf[nt] = *(const short8*)&Bb[rbB + nt * 128];
        l0 = *(const short8*)&lbs[0][k0 + quad * 8];
        l1 = *(const short8*)&lbs[1][k0 + quad * 8];
    };

    auto cluster = [&](const short8 (&af)[4], const short8 (&bf)[4],
                       const short8& l0, const short8& l1) {
        __builtin_amdgcn_s_setprio(1);
#pragma unroll
        for (int mt = 0; mt < 4; ++mt) {
            short8 a0 = hmul8(af[mt], l0);
            short8 a1 = hmul8(af[mt], l1);
#pragma unroll
            for (int nt = 0; nt < 4; ++nt) {
                acc0[mt][nt] = __builtin_amdgcn_mfma_f32_16x16x32_f16(
                    __builtin_bit_cast(half8, a0),
                    __builtin_bit_cast(half8, bf[nt]), acc0[mt][nt], 0, 0, 0);
                acc1[mt][nt] = __builtin_amdgcn_mfma_f32_16x16x32_f16(
                    __builtin_bit_cast(half8, a1),
                    __builtin_bit_cast(half8, bf[nt]), acc1[mt][nt], 0, 0, 0);
            }
        }
        __builtin_amdgcn_s_setprio(0);
    };

    __syncthreads();        // lbs/sred visible to all waves (nothing in VMEM queue yet)

    stageT(0, 0);
    stageT(1, 32);
    asm volatile("s_waitcnt vmcnt(4)" ::: "memory");   // buf0 staged (buf1's 4 in flight)
    __builtin_amdgcn_s_barrier();
    __builtin_amdgcn_sched_barrier(0);

    short8 afA[4], bfA[4], lvA0, lvA1;
    short8 afB[4], bfB[4], lvB0, lvB1;
    readFrags(afA, bfA, lvA0, lvA1, 0, 0);

    int bc = 0, bn = 1, bs = 2;   // buf holding cur-k / next-k / free(staging)
    for (int i = 0; i < 24; i += 2) {
        // ---- even half: compute set A (k = 32i), read set B (k+32) ----
        if (i + 1 < 24) {
            asm volatile("s_waitcnt vmcnt(0)" ::: "memory");  // bn staged (issued 1 iter ago)
            __builtin_amdgcn_s_barrier();
            __builtin_amdgcn_sched_barrier(0);
            readFrags(afB, bfB, lvB0, lvB1, bn, (i + 1) * 32);
            if (i + 2 < 24) stageT(bs, (i + 2) * 32);
            int t = bc; bc = bn; bn = bs; bs = t;
            __builtin_amdgcn_sched_barrier(0);
        }
        cluster(afA, bfA, lvA0, lvA1);
        // ---- odd half: compute set B (k = 32(i+1)), read set A (k+64) ----
        if (i + 2 < 24) {
            asm volatile("s_waitcnt vmcnt(0)" ::: "memory");
            __builtin_amdgcn_s_barrier();
            __builtin_amdgcn_sched_barrier(0);
            readFrags(afA, bfA, lvA0, lvA1, bn, (i + 2) * 32);
            if (i + 3 < 24) stageT(bs, (i + 3) * 32);
            int t = bc; bc = bn; bn = bs; bs = t;
            __builtin_amdgcn_sched_barrier(0);
        }
        cluster(afB, bfB, lvB0, lvB1);
    }

    // ---- epilogue: per c: h = relu(P + Aw + Bc); sacc[w][r] += h*W2[j][r] ----
    // j = jt + wm*64 + mt*16 + quad*4 + reg ; w = m0 + wn*64 + nt*16 + l15
    float bcv0[4][4], bcv1[4][4], w2v[4][4][3];
#pragma unroll
    for (int mt = 0; mt < 4; ++mt) {
        const int jb = jt + wm * 64 + mt * 16 + quad * 4;
        float4 b4 = *(const float4*)&Bc[(size_t)c0 * Hd + jb];
        bcv0[mt][0] = b4.x; bcv0[mt][1] = b4.y; bcv0[mt][2] = b4.z; bcv0[mt][3] = b4.w;
        float4 b5 = *(const float4*)&Bc[(size_t)(c0 + 1) * Hd + jb];
        bcv1[mt][0] = b5.x; bcv1[mt][1] = b5.y; bcv1[mt][2] = b5.z; bcv1[mt][3] = b5.w;
#pragma unroll
        for (int reg = 0; reg < 4; ++reg)
#pragma unroll
            for (int r = 0; r < 3; ++r) w2v[mt][reg][r] = W2[(jb + reg) * 3 + r];
    }

    auto reduce_c = [&](const f32x4 (&ac)[4][4], const float (&bcv)[4][4], int cc) {
#pragma unroll
        for (int nt = 0; nt < 4; ++nt) {
            const int w = m0 + wn * 64 + nt * 16 + l15;
            const float* awp = Aw + (size_t)w * Hd + jt + wm * 64;
            float s0 = 0.f, s1 = 0.f, s2 = 0.f;
#pragma unroll
            for (int mt = 0; mt < 4; ++mt) {
                float4 a4 = *(const float4*)&awp[mt * 16 + quad * 4];
                float av[4] = {a4.x, a4.y, a4.z, a4.w};
#pragma unroll
                for (int reg = 0; reg < 4; ++reg) {
                    float h = ac[mt][nt][reg] + av[reg] + bcv[mt][reg];
                    h = h > 0.f ? h : 0.f;
                    s0 += h * w2v[mt][reg][0];
                    s1 += h * w2v[mt][reg][1];
                    s2 += h * w2v[mt][reg][2];
                }
            }
            s0 += __shfl_xor(s0, 16); s0 += __shfl_xor(s0, 32);
            s1 += __shfl_xor(s1, 16); s1 += __shfl_xor(s1, 32);
            s2 += __shfl_xor(s2, 16); s2 += __shfl_xor(s2, 32);
            if (quad == 0) {
                const int wl = wn * 64 + nt * 16 + l15;
                atomicAdd(&sred[cc * 384 + wl * 3 + 0], s0);   // LDS, 2-way (wm)
                atomicAdd(&sred[cc * 384 + wl * 3 + 1], s1);
                atomicAdd(&sred[cc * 384 + wl * 3 + 2], s2);
            }
        }
    };
    reduce_c(acc0, bcv0, 0);
    reduce_c(acc1, bcv1, 1);
    __syncthreads();

    // non-atomic store to per-jx scratch slot (disjoint across blocks)
    float* slab = scr + ((size_t)jx * 1024 * Cn + (size_t)m0 * Cn) * 3;
    for (int i = tid; i < 2 * 128 * 3; i += 256) {
        int cc = i / 384, j = i - cc * 384;
        int wl = j / 3, r = j - wl * 3;
        slab[((size_t)wl * Cn + (c0 + cc)) * 3 + r] = sred[i];
    }
}

// ---------- final: out = b2 + sum_jx scr[jx] ----------
__global__ __launch_bounds__(256)
void k_scores(const float* __restrict__ scr, const float* __restrict__ b2,
              float* __restrict__ out, int n) {
    int i = blockIdx.x * 256 + threadIdx.x;
    if (i >= n) return;
    float v = b2[i % 3];
#pragma unroll
    for (int s = 0; s < 6; ++s) v += scr[(size_t)s * n + i];
    out[i] = v;
}

extern "C" void kernel_launch(void* const* d_in, const int* in_sizes, int n_in,
                              void* d_out, int out_size, void* d_ws, size_t ws_size,
                              hipStream_t stream) {
    const float* tok    = (const float*)d_in[0];
    const int*   wmask  = (const int*)d_in[1];
    const float* labe   = (const float*)d_in[3];
    const float* W_tok  = (const float*)d_in[4];
    const float* b_tok  = (const float*)d_in[5];
    const float* W_lab  = (const float*)d_in[6];
    const float* b_lab  = (const float*)d_in[7];
    const float* W1     = (const float*)d_in[8];
    const float* b1     = (const float*)d_in[9];
    const float* W2     = (const float*)d_in[10];
    const float* b2     = (const float*)d_in[11];
    float* out = (float*)d_out;

    const int L  = in_sizes[1];
    const int Wd = out_size / (Cn * 3);   // 1024

    char* ws = (char*)d_ws;
    size_t off = 0;
    auto alloc = [&](size_t bytes) { char* p = ws + off; off += (bytes + 255) & ~(size_t)255; return p; };
    // ---- persistent region ----
    int*   widx  = (int*)alloc(4096);
    float* Abuf  = (float*)alloc((size_t)Wd * Hd * 4);
    float* Bbuf  = (float*)alloc((size_t)Cn * Hd * 4);
    us* W1ct  = (us*)alloc((size_t)Hd * Hd * 2);   // fp16
    us* W1cl  = (us*)alloc((size_t)Hd * Hd * 2);   // unused
    us* t1b   = (us*)alloc((size_t)Wd * Hd * 2);   // fp16
    us* lb1b  = (us*)alloc((size_t)Cn * Hd * 2);   // fp16
    float* scr = (float*)alloc((size_t)6 * Wd * Cn * 3 * 4);   // 4.72 MB partials
    // ---- scratch region ----
    us* WtTh  = (us*)alloc((size_t)H2 * Hd * 2);
    us* WtTl  = (us*)alloc((size_t)H2 * Hd * 2);
    us* WlTh  = (us*)alloc((size_t)H2 * Hd * 2);
    us* WlTl  = (us*)alloc((size_t)H2 * Hd * 2);
    us* W1aTh = (us*)alloc((size_t)Hd * Hd * 2);
    us* W1aTl = (us*)alloc((size_t)Hd * Hd * 2);
    us* W1bTh = (us*)alloc((size_t)Hd * Hd * 2);
    us* W1bTl = (us*)alloc((size_t)Hd * Hd * 2);
    us* weh   = (us*)alloc((size_t)Wd * Hd * 2);
    us* wel   = (us*)alloc((size_t)Wd * Hd * 2);
    us* lah   = (us*)alloc((size_t)Cn * Hd * 2);
    us* lal   = (us*)alloc((size_t)Cn * Hd * 2);
    us* t0h   = (us*)alloc((size_t)Wd * Hd * 2);
    us* t0l   = (us*)alloc((size_t)Wd * Hd * 2);
    us* lb0h  = (us*)alloc((size_t)Cn * Hd * 2);
    us* lb0l  = (us*)alloc((size_t)Cn * Hd * 2);

    // 1) widx = -1 (kernel) + scatter + merged we/labe split
    k_init<<<(Wd + 255) / 256, 256, 0, stream>>>(widx, Wd);
    k_scatter<<<(L + 255) / 256, 256, 0, stream>>>(wmask, widx, L, Wd);
    k_build_we_labe<<<(Wd * 192 + Cn * 192 + 255) / 256, 256, 0, stream>>>(
        (const float4*)tok, widx, weh, wel, Wd, (const float4*)labe, lah, lal);

    // 2) batched weight transpose+split (W1c -> fp16)
    TSArgs ts;
    ts.src[0] = W_tok;  ts.th[0] = WtTh;  ts.tl[0] = WtTl;  ts.ld[0] = H2; ts.N[0] = H2; ts.fmt[0] = 0;
    ts.src[1] = W_lab;  ts.th[1] = WlTh;  ts.tl[1] = WlTl;  ts.ld[1] = H2; ts.N[1] = H2; ts.fmt[1] = 0;
    ts.src[2] = W1;                         ts.th[2] = W1aTh; ts.tl[2] = W1aTl; ts.ld[2] = Hd; ts.N[2] = Hd; ts.fmt[2] = 0;
    ts.src[3] = W1 + (size_t)Hd * Hd;       ts.th[3] = W1bTh; ts.tl[3] = W1bTl; ts.ld[3] = Hd; ts.N[3] = Hd; ts.fmt[3] = 0;
    ts.src[4] = W1 + (size_t)2 * Hd * Hd;   ts.th[4] = W1ct;  ts.tl[4] = W1cl;  ts.ld[4] = Hd; ts.N[4] = Hd; ts.fmt[4] = 1;
    k_tsplit<<<dim3(H2 / 64, Hd / 64, 5), 256, 0, stream>>>(ts);

    // 3) t = we @ W_tok + b_tok -> fused t0 hi/lo + t1b fp16
    k_gemm3<<<dim3(H2 / 64, Wd / 64), 256, 0, stream>>>(weh, wel, WtTh, WtTl, b_tok,
                                                        nullptr, t0h, t0l, t1b, 1, Hd, H2, Hd);

    // 4) lb = labe @ W_lab + b_lab (64x1536), z=1 fused -> lb0 split + lb1b fp16
    k_gemm3<<<dim3(H2 / 64, 1), 256, 0, stream>>>(lah, lal, WlTh, WlTl, b_lab,
                                                  nullptr, lb0h, lb0l, lb1b, 1, Hd, H2, Hd);

    // 5) Aw = t0 @ W1a (1024x768) -> fused f32 write
    k_gemm3<<<dim3(Hd / 64, Wd / 64), 256, 0, stream>>>(t0h, t0l, W1aTh, W1aTl, nullptr,
                                                        Abuf, nullptr, nullptr, nullptr, 0, 0, Hd, Hd);

    // 6) Bc = lb0 @ W1b + b1 (64x768), z=1 fused -> f32 Bbuf
    k_gemm3<<<dim3(Hd / 64, 1), 256, 0, stream>>>(lb0h, lb0l, W1bTh, W1bTl, b1,
                                                  Bbuf, nullptr, nullptr, nullptr, 0, 0, Hd, Hd);

    // 7) fused fp16 P-GEMM v10 (session-final structure) -> scratch
    k_mfma10<<<1536, 256, 0, stream>>>(t1b, W1ct, lb1b, Abuf, Bbuf, W2, scr);

    // 8) out = b2 + sum_jx scr
    k_scores<<<(Wd * Cn * 3 + 255) / 256, 256, 0, stream>>>(scr, b2, out, Wd * Cn * 3);
}

// Round 11
// 251.251 us; speedup vs baseline: 1.5125x; 1.0356x over previous
//
#include <hip/hip_runtime.h>
#include <hip/hip_bf16.h>

static constexpr int Hd = 768;    // H
static constexpr int H2 = 1536;   // 2H
static constexpr int Cn = 64;     // C (labels)

typedef __attribute__((ext_vector_type(8))) short short8;
typedef __attribute__((ext_vector_type(8))) _Float16 half8;
typedef __attribute__((ext_vector_type(4))) float f32x4;
typedef unsigned short us;

__device__ inline void split1(float x, us& h, us& l) {
    __hip_bfloat16 hb = __float2bfloat16(x);
    float hf = __bfloat162float(hb);
    __hip_bfloat16 lb_ = __float2bfloat16(x - hf);
    h = *reinterpret_cast<us*>(&hb);
    l = *reinterpret_cast<us*>(&lb_);
}

__device__ inline us f2b(float x) {
    __hip_bfloat16 b = __float2bfloat16(x);
    return *reinterpret_cast<us*>(&b);
}

__device__ inline us f2h(float x) {
    _Float16 h = (_Float16)x;
    return *reinterpret_cast<us*>(&h);
}

// packed fp16 elementwise product: 4x v_pk_mul_f16
__device__ inline short8 hmul8(short8 a, short8 b) {
    half8 x = __builtin_bit_cast(half8, a);
    half8 y = __builtin_bit_cast(half8, b);
    half8 r = x * y;
    return __builtin_bit_cast(short8, r);
}

__device__ inline void gload16(const void* g, void* l) {
    __builtin_amdgcn_global_load_lds(
        (const __attribute__((address_space(1))) unsigned int*)g,
        (__attribute__((address_space(3))) unsigned int*)l, 16, 0, 0);
}

// ---------------- init: widx = -1 (kernel — graph-capture safe) ----------------
__global__ void k_init(int* widx, int Wd) {
    int i = blockIdx.x * 256 + threadIdx.x;
    if (i < Wd) widx[i] = -1;
}

__global__ void k_scatter(const int* __restrict__ wmask, int* widx, int L, int Wd) {
    int i = blockIdx.x * 256 + threadIdx.x;
    if (i < L) {
        int m = wmask[i];
        if (m > 0 && m <= Wd) atomicMax(&widx[m - 1], i);  // last token wins
    }
}

// build we (scatter-pooled tok rows) as hi/lo bf16 split, AND labe split (merged kernel)
__global__ void k_build_we_labe(const float4* __restrict__ tok, const int* __restrict__ widx,
                                us* __restrict__ weh, us* __restrict__ wel, int Wd,
                                const float4* __restrict__ labe,
                                us* __restrict__ lah, us* __restrict__ lal) {
    int gi = blockIdx.x * 256 + threadIdx.x;
    const int nwe = Wd * 192;                 // we range (float4 granularity)
    float4 v;
    size_t o;
    us hh[4], ll[4];
    if (gi < nwe) {
        int w = gi / 192, c4 = gi - w * 192;
        int idx = widx[w];
        v = (idx >= 0) ? tok[idx * 192 + c4] : float4{0.f, 0.f, 0.f, 0.f};
        o = (size_t)w * Hd + c4 * 4;
        split1(v.x, hh[0], ll[0]);
        split1(v.y, hh[1], ll[1]);
        split1(v.z, hh[2], ll[2]);
        split1(v.w, hh[3], ll[3]);
        *(ushort4*)&weh[o] = ushort4{hh[0], hh[1], hh[2], hh[3]};
        *(ushort4*)&wel[o] = ushort4{ll[0], ll[1], ll[2], ll[3]};
    } else {
        int i = gi - nwe;                     // labe range: Cn*192 float4s
        if (i >= Cn * 192) return;
        v = labe[i];
        o = (size_t)i * 4;
        split1(v.x, hh[0], ll[0]);
        split1(v.y, hh[1], ll[1]);
        split1(v.z, hh[2], ll[2]);
        split1(v.w, hh[3], ll[3]);
        *(ushort4*)&lah[o] = ushort4{hh[0], hh[1], hh[2], hh[3]};
        *(ushort4*)&lal[o] = ushort4{ll[0], ll[1], ll[2], ll[3]};
    }
}

// ---------- batched transpose + split: T[n][k]; fmt=0 bf16 hi/lo, fmt=1 fp16 (Th only) ----------
struct TSArgs {
    const float* src[5];
    us* th[5];
    us* tl[5];
    int ld[5];
    int N[5];
    int fmt[5];
};
__global__ __launch_bounds__(256)
void k_tsplit(TSArgs a) {
    __shared__ float tile[64][65];
    const int z = blockIdx.z;
    const int n0 = blockIdx.x * 64, k0 = blockIdx.y * 64;
    if (n0 >= a.N[z]) return;
    const float* W = a.src[z];
    const int ld = a.ld[z];
    for (int idx = threadIdx.x; idx < 4096; idx += 256) {
        int kk = idx >> 6, nn = idx & 63;
        tile[kk][nn] = W[(size_t)(k0 + kk) * ld + n0 + nn];
    }
    __syncthreads();
    us* Th = a.th[z];
    us* Tl = a.tl[z];
    const int fmt = a.fmt[z];
    for (int idx = threadIdx.x; idx < 4096; idx += 256) {
        int nn = idx >> 6, kk = idx & 63;
        size_t o = (size_t)(n0 + nn) * Hd + k0 + kk;
        if (fmt) {
            Th[o] = f2h(tile[kk][nn]);
        } else {
            us h, l;
            split1(tile[kk][nn], h, l);
            Th[o] = h;
            Tl[o] = l;
        }
    }
}

// ---------- split-bf16 GEMM, LDS double-buffered, K-split partials (small Ms) ----------
__global__ __launch_bounds__(256)
void k_gemm2(const us* __restrict__ Ah, const us* __restrict__ Al,
             const us* __restrict__ BhT, const us* __restrict__ BlT,
             float* __restrict__ Cpart, int M, int N, int K) {
    __shared__ __align__(16) us S[2][4][64 * 32];
    const int tid = threadIdx.x, wave = tid >> 6, lane = tid & 63;
    const int quad = lane >> 4, l15 = lane & 15;
    const int wm = wave & 1, wn = wave >> 1;
    const int m0 = blockIdx.y * 64, n0 = blockIdx.x * 64;
    const int Ks = K / gridDim.z, kbeg = blockIdx.z * Ks, kend = kbeg + Ks;
    float* C = Cpart + (size_t)blockIdx.z * M * N;

    const int srow = wave * 16 + (lane >> 2), soff = (lane & 3) * 8;
    const size_t gaB = (size_t)(m0 + srow) * K + soff;
    const size_t gbB = (size_t)(n0 + srow) * K + soff;
    const int lo = wave * 16 * 32;

    f32x4 acc[2][2];
#pragma unroll
    for (int a = 0; a < 2; ++a)
#pragma unroll
        for (int b = 0; b < 2; ++b) acc[a][b] = (f32x4){0.f, 0.f, 0.f, 0.f};

    auto stage = [&](int p, int k0) {
        gload16(Ah + gaB + k0, &S[p][0][lo]);
        gload16(Al + gaB + k0, &S[p][1][lo]);
        gload16(BhT + gbB + k0, &S[p][2][lo]);
        gload16(BlT + gbB + k0, &S[p][3][lo]);
    };

    int p = 0;
    stage(0, kbeg);
    for (int k0 = kbeg; k0 < kend; k0 += 32) {
        __syncthreads();
        if (k0 + 32 < kend) stage(p ^ 1, k0 + 32);
        short8 ah[2], al[2], bh[2], bl[2];
#pragma unroll
        for (int mt = 0; mt < 2; ++mt) {
            int off = (wm * 32 + mt * 16 + l15) * 32 + quad * 8;
            ah[mt] = *(const short8*)&S[p][0][off];
            al[mt] = *(const short8*)&S[p][1][off];
        }
#pragma unroll
        for (int nt = 0; nt < 2; ++nt) {
            int off = (wn * 32 + nt * 16 + l15) * 32 + quad * 8;
            bh[nt] = *(const short8*)&S[p][2][off];
            bl[nt] = *(const short8*)&S[p][3][off];
        }
#pragma unroll
        for (int mt = 0; mt < 2; ++mt)
#pragma unroll
            for (int nt = 0; nt < 2; ++nt) {
                acc[mt][nt] = __builtin_amdgcn_mfma_f32_16x16x32_bf16(al[mt], bh[nt], acc[mt][nt], 0, 0, 0);
                acc[mt][nt] = __builtin_amdgcn_mfma_f32_16x16x32_bf16(ah[mt], bl[nt], acc[mt][nt], 0, 0, 0);
                acc[mt][nt] = __builtin_amdgcn_mfma_f32_16x16x32_bf16(ah[mt], bh[nt], acc[mt][nt], 0, 0, 0);
            }
        p ^= 1;
    }
#pragma unroll
    for (int mt = 0; mt < 2; ++mt)
#pragma unroll
        for (int nt = 0; nt < 2; ++nt) {
            int col = n0 + wn * 32 + nt * 16 + l15;
#pragma unroll
            for (int reg = 0; reg < 4; ++reg) {
                int row = m0 + wm * 32 + mt * 16 + quad * 4 + reg;
                C[(size_t)row * N + col] = acc[mt][nt][reg];
            }
        }
}

// ---------- split-bf16 GEMM, z=1, fused outputs (bias + f32 / hi-lo split / 16-bit) ----------
__global__ __launch_bounds__(256)
void k_gemm3(const us* __restrict__ Ah, const us* __restrict__ Al,
             const us* __restrict__ BhT, const us* __restrict__ BlT,
             const float* __restrict__ bias, float* __restrict__ outF,
             us* __restrict__ sh, us* __restrict__ sl, us* __restrict__ bh16,
             int fp16out, int scols, int N, int K) {
    __shared__ __align__(16) us S[2][4][64 * 32];
    const int tid = threadIdx.x, wave = tid >> 6, lane = tid & 63;
    const int quad = lane >> 4, l15 = lane & 15;
    const int wm = wave & 1, wn = wave >> 1;
    const int m0 = blockIdx.y * 64, n0 = blockIdx.x * 64;

    const int srow = wave * 16 + (lane >> 2), soff = (lane & 3) * 8;
    const size_t gaB = (size_t)(m0 + srow) * K + soff;
    const size_t gbB = (size_t)(n0 + srow) * K + soff;
    const int lo = wave * 16 * 32;

    f32x4 acc[2][2];
#pragma unroll
    for (int a = 0; a < 2; ++a)
#pragma unroll
        for (int b = 0; b < 2; ++b) acc[a][b] = (f32x4){0.f, 0.f, 0.f, 0.f};

    auto stage = [&](int p, int k0) {
        gload16(Ah + gaB + k0, &S[p][0][lo]);
        gload16(Al + gaB + k0, &S[p][1][lo]);
        gload16(BhT + gbB + k0, &S[p][2][lo]);
        gload16(BlT + gbB + k0, &S[p][3][lo]);
    };

    int p = 0;
    stage(0, 0);
    for (int k0 = 0; k0 < K; k0 += 32) {
        __syncthreads();
        if (k0 + 32 < K) stage(p ^ 1, k0 + 32);
        short8 ah[2], al[2], bh[2], bl[2];
#pragma unroll
        for (int mt = 0; mt < 2; ++mt) {
            int off = (wm * 32 + mt * 16 + l15) * 32 + quad * 8;
            ah[mt] = *(const short8*)&S[p][0][off];
            al[mt] = *(const short8*)&S[p][1][off];
        }
#pragma unroll
        for (int nt = 0; nt < 2; ++nt) {
            int off = (wn * 32 + nt * 16 + l15) * 32 + quad * 8;
            bh[nt] = *(const short8*)&S[p][2][off];
            bl[nt] = *(const short8*)&S[p][3][off];
        }
#pragma unroll
        for (int mt = 0; mt < 2; ++mt)
#pragma unroll
            for (int nt = 0; nt < 2; ++nt) {
                acc[mt][nt] = __builtin_amdgcn_mfma_f32_16x16x32_bf16(al[mt], bh[nt], acc[mt][nt], 0, 0, 0);
                acc[mt][nt] = __builtin_amdgcn_mfma_f32_16x16x32_bf16(ah[mt], bl[nt], acc[mt][nt], 0, 0, 0);
                acc[mt][nt] = __builtin_amdgcn_mfma_f32_16x16x32_bf16(ah[mt], bh[nt], acc[mt][nt], 0, 0, 0);
            }
        p ^= 1;
    }
#pragma unroll
    for (int mt = 0; mt < 2; ++mt)
#pragma unroll
        for (int nt = 0; nt < 2; ++nt) {
            int col = n0 + wn * 32 + nt * 16 + l15;
            float bb = bias ? bias[col] : 0.f;
#pragma unroll
            for (int reg = 0; reg < 4; ++reg) {
                int row = m0 + wm * 32 + mt * 16 + quad * 4 + reg;
                float v = acc[mt][nt][reg] + bb;
                if (outF) outF[(size_t)row * N + col] = v;
                if (sh) {
                    if (col < scols) {
                        us h, l;
                        split1(v, h, l);
                        size_t o = (size_t)row * scols + col;
                        sh[o] = h;
                        sl[o] = l;
                    } else if (bh16) {
                        bh16[(size_t)row * scols + (col - scols)] = fp16out ? f2h(v) : f2b(v);
                    }
                }
            }
        }
}

// ---------- reduce partials + bias; f32 out + hi/lo split (col<scols) + 16-bit (col>=scols) ----------
__global__ __launch_bounds__(256)
void k_reduce(const float* __restrict__ part, int S, int MN, int N,
              const float* __restrict__ bias, float* __restrict__ outF,
              us* __restrict__ sh, us* __restrict__ sl, int scols,
              us* __restrict__ bh16, int fp16out) {
    int i = blockIdx.x * 256 + threadIdx.x;
    if (i >= MN) return;
    float v = 0.f;
    for (int s = 0; s < S; ++s) v += part[(size_t)s * MN + i];
    int row = i / N, col = i - row * N;
    if (bias) v += bias[col];
    if (outF) outF[i] = v;
    if (col < scols) {
        if (sh) {
            us h, l;
            split1(v, h, l);
            size_t o = (size_t)row * scols + col;
            sh[o] = h;
            sl[o] = l;
        }
    } else if (bh16) {
        bh16[(size_t)row * scols + (col - scols)] = fp16out ? f2h(v) : f2b(v);
    }
}

// ---------------- P-GEMM v10 (FINAL): reg double-buffered fragments, 2-label tiles ----------------
// Session verdict (R1-R10): v10's 655 TF effective (27% MfmaUtil) is this op's structural
// plateau. Falsified alternatives: counted-vmcnt alone (v9, NULL), 3-wave occupancy
// reshape (v11, -27%), barrier-free private slices (v12, -119%), 256^2 8-phase template
// (v13 spilled; v15 clean test -31%), small-tile fine phases (v14, -42%).
// R10 lesson: small-M GEMMs (M=64) MUST stay K-split (z=8) — z=1 serializes K on 24
// blocks and costs ~10us.
__global__ __launch_bounds__(256, 2)
void k_mfma10(const us* __restrict__ t1b,   // (1024,768) fp16
              const us* __restrict__ W1ct,  // (768,768) fp16 [j][k]
              const us* __restrict__ lb1b,  // (64,768) fp16
              const float* __restrict__ Aw, // (1024,768) f32
              const float* __restrict__ Bc, // (64,768) f32 (includes b1)
              const float* __restrict__ W2, // (768,3) f32
              float* __restrict__ scr) {    // (6,1024,64,3) f32 partials
    __shared__ __align__(16) us As[3][4096];   // [q][row][8] chunk-major, 8 KB per buf
    __shared__ __align__(16) us Bs[3][4096];
    __shared__ __align__(16) us lbs[2][Hd];    // lb1 rows for the 2 labels
    __shared__ float sred[2 * 128 * 3];

    const int tid = threadIdx.x, wave = tid >> 6, lane = tid & 63;
    const int quad = lane >> 4, l15 = lane & 15;
    const int wm = wave & 1, wn = wave >> 1;

    // L2-locality decode: b = xcd + 8*(jx*32 + cp); my = xcd
    const int b = blockIdx.x;
    const int xcd = b & 7, slot = b >> 3;    // slot 0..191
    const int jx = slot >> 5;                // 0..5
    const int cp = slot & 31;                // 0..31 (varies fastest)
    const int c0 = cp * 2;
    const int jt = jx * 128, m0 = xcd * 128;

    for (int i = tid; i < 2 * 128 * 3; i += 256) sred[i] = 0.f;
    if (tid < 192) {                          // stage lb1 rows c0,c0+1 (3 KB)
        int cc = tid / 96, o = (tid - cc * 96) * 8;
        *(short8*)&lbs[cc][o] = *(const short8*)&lb1b[(size_t)(c0 + cc) * Hd + o];
    }

    // staging map: wave issues chunks i=wave and i=wave+4; i -> (q=i>>1, rhalf=i&1)
    const int srow = (wave & 1) * 64 + lane;
    const int skq = (wave >> 1) * 8;          // k offset of chunk q within the 32-k step
    const us* gA = W1ct + (size_t)(jt + srow) * Hd + skq;
    const us* gB = t1b + (size_t)(m0 + srow) * Hd + skq;

    f32x4 acc0[4][4], acc1[4][4];
#pragma unroll
    for (int mt = 0; mt < 4; ++mt)
#pragma unroll
        for (int nt = 0; nt < 4; ++nt) {
            acc0[mt][nt] = (f32x4){0.f, 0.f, 0.f, 0.f};
            acc1[mt][nt] = (f32x4){0.f, 0.f, 0.f, 0.f};
        }

    auto stageT = [&](int p, int k0) {
        gload16(gA + k0,      &As[p][wave * 512]);
        gload16(gA + k0 + 16, &As[p][(wave + 4) * 512]);
        gload16(gB + k0,      &Bs[p][wave * 512]);
        gload16(gB + k0 + 16, &Bs[p][(wave + 4) * 512]);
    };

    // fragment read bases: element (q, row) at us-index q*1024 + row*8
    const int rbA = quad * 1024 + (wm * 64 + l15) * 8;
    const int rbB = quad * 1024 + (wn * 64 + l15) * 8;

    auto readFrags = [&](short8 (&af)[4], short8 (&bf)[4], short8& l0, short8& l1,
                         int buf, int k0) {
        const us* Ab = &As[buf][0];
        const us* Bb = &Bs[buf][0];
#pragma unroll
        for (int mt = 0; mt < 4; ++mt) af[mt] = *(const short8*)&Ab[rbA + mt * 128];
#pragma unroll
        for (int nt = 0; nt < 4; ++nt) bf[nt] = *(const short8*)&Bb[rbB + nt * 128];
        l0 = *(const short8*)&lbs[0][k0 + quad * 8];
        l1 = *(const short8*)&lbs[1][k0 + quad * 8];
    };

    auto cluster = [&](const short8 (&af)[4], const short8 (&bf)[4],
                       const short8& l0, const short8& l1) {
        __builtin_amdgcn_s_setprio(1);
#pragma unroll
        for (int mt = 0; mt < 4; ++mt) {
            short8 a0 = hmul8(af[mt], l0);
            short8 a1 = hmul8(af[mt], l1);
#pragma unroll
            for (int nt = 0; nt < 4; ++nt) {
                acc0[mt][nt] = __builtin_amdgcn_mfma_f32_16x16x32_f16(
                    __builtin_bit_cast(half8, a0),
                    __builtin_bit_cast(half8, bf[nt]), acc0[mt][nt], 0, 0, 0);
                acc1[mt][nt] = __builtin_amdgcn_mfma_f32_16x16x32_f16(
                    __builtin_bit_cast(half8, a1),
                    __builtin_bit_cast(half8, bf[nt]), acc1[mt][nt], 0, 0, 0);
            }
        }
        __builtin_amdgcn_s_setprio(0);
    };

    __syncthreads();        // lbs/sred visible to all waves (nothing in VMEM queue yet)

    stageT(0, 0);
    stageT(1, 32);
    asm volatile("s_waitcnt vmcnt(4)" ::: "memory");   // buf0 staged (buf1's 4 in flight)
    __builtin_amdgcn_s_barrier();
    __builtin_amdgcn_sched_barrier(0);

    short8 afA[4], bfA[4], lvA0, lvA1;
    short8 afB[4], bfB[4], lvB0, lvB1;
    readFrags(afA, bfA, lvA0, lvA1, 0, 0);

    int bc = 0, bn = 1, bs = 2;   // buf holding cur-k / next-k / free(staging)
    for (int i = 0; i < 24; i += 2) {
        // ---- even half: compute set A (k = 32i), read set B (k+32) ----
        if (i + 1 < 24) {
            asm volatile("s_waitcnt vmcnt(0)" ::: "memory");  // bn staged (issued 1 iter ago)
            __builtin_amdgcn_s_barrier();
            __builtin_amdgcn_sched_barrier(0);
            readFrags(afB, bfB, lvB0, lvB1, bn, (i + 1) * 32);
            if (i + 2 < 24) stageT(bs, (i + 2) * 32);
            int t = bc; bc = bn; bn = bs; bs = t;
            __builtin_amdgcn_sched_barrier(0);
        }
        cluster(afA, bfA, lvA0, lvA1);
        // ---- odd half: compute set B (k = 32(i+1)), read set A (k+64) ----
        if (i + 2 < 24) {
            asm volatile("s_waitcnt vmcnt(0)" ::: "memory");
            __builtin_amdgcn_s_barrier();
            __builtin_amdgcn_sched_barrier(0);
            readFrags(afA, bfA, lvA0, lvA1, bn, (i + 2) * 32);
            if (i + 3 < 24) stageT(bs, (i + 3) * 32);
            int t = bc; bc = bn; bn = bs; bs = t;
            __builtin_amdgcn_sched_barrier(0);
        }
        cluster(afB, bfB, lvB0, lvB1);
    }

    // ---- epilogue: per c: h = relu(P + Aw + Bc); sacc[w][r] += h*W2[j][r] ----
    // j = jt + wm*64 + mt*16 + quad*4 + reg ; w = m0 + wn*64 + nt*16 + l15
    float bcv0[4][4], bcv1[4][4], w2v[4][4][3];
#pragma unroll
    for (int mt = 0; mt < 4; ++mt) {
        const int jb = jt + wm * 64 + mt * 16 + quad * 4;
        float4 b4 = *(const float4*)&Bc[(size_t)c0 * Hd + jb];
        bcv0[mt][0] = b4.x; bcv0[mt][1] = b4.y; bcv0[mt][2] = b4.z; bcv0[mt][3] = b4.w;
        float4 b5 = *(const float4*)&Bc[(size_t)(c0 + 1) * Hd + jb];
        bcv1[mt][0] = b5.x; bcv1[mt][1] = b5.y; bcv1[mt][2] = b5.z; bcv1[mt][3] = b5.w;
#pragma unroll
        for (int reg = 0; reg < 4; ++reg)
#pragma unroll
            for (int r = 0; r < 3; ++r) w2v[mt][reg][r] = W2[(jb + reg) * 3 + r];
    }

    auto reduce_c = [&](const f32x4 (&ac)[4][4], const float (&bcv)[4][4], int cc) {
#pragma unroll
        for (int nt = 0; nt < 4; ++nt) {
            const int w = m0 + wn * 64 + nt * 16 + l15;
            const float* awp = Aw + (size_t)w * Hd + jt + wm * 64;
            float s0 = 0.f, s1 = 0.f, s2 = 0.f;
#pragma unroll
            for (int mt = 0; mt < 4; ++mt) {
                float4 a4 = *(const float4*)&awp[mt * 16 + quad * 4];
                float av[4] = {a4.x, a4.y, a4.z, a4.w};
#pragma unroll
                for (int reg = 0; reg < 4; ++reg) {
                    float h = ac[mt][nt][reg] + av[reg] + bcv[mt][reg];
                    h = h > 0.f ? h : 0.f;
                    s0 += h * w2v[mt][reg][0];
                    s1 += h * w2v[mt][reg][1];
                    s2 += h * w2v[mt][reg][2];
                }
            }
            s0 += __shfl_xor(s0, 16); s0 += __shfl_xor(s0, 32);
            s1 += __shfl_xor(s1, 16); s1 += __shfl_xor(s1, 32);
            s2 += __shfl_xor(s2, 16); s2 += __shfl_xor(s2, 32);
            if (quad == 0) {
                const int wl = wn * 64 + nt * 16 + l15;
                atomicAdd(&sred[cc * 384 + wl * 3 + 0], s0);   // LDS, 2-way (wm)
                atomicAdd(&sred[cc * 384 + wl * 3 + 1], s1);
                atomicAdd(&sred[cc * 384 + wl * 3 + 2], s2);
            }
        }
    };
    reduce_c(acc0, bcv0, 0);
    reduce_c(acc1, bcv1, 1);
    __syncthreads();

    // non-atomic store to per-jx scratch slot (disjoint across blocks)
    float* slab = scr + ((size_t)jx * 1024 * Cn + (size_t)m0 * Cn) * 3;
    for (int i = tid; i < 2 * 128 * 3; i += 256) {
        int cc = i / 384, j = i - cc * 384;
        int wl = j / 3, r = j - wl * 3;
        slab[((size_t)wl * Cn + (c0 + cc)) * 3 + r] = sred[i];
    }
}

// ---------- final: out = b2 + sum_jx scr[jx] ----------
__global__ __launch_bounds__(256)
void k_scores(const float* __restrict__ scr, const float* __restrict__ b2,
              float* __restrict__ out, int n) {
    int i = blockIdx.x * 256 + threadIdx.x;
    if (i >= n) return;
    float v = b2[i % 3];
#pragma unroll
    for (int s = 0; s < 6; ++s) v += scr[(size_t)s * n + i];
    out[i] = v;
}

extern "C" void kernel_launch(void* const* d_in, const int* in_sizes, int n_in,
                              void* d_out, int out_size, void* d_ws, size_t ws_size,
                              hipStream_t stream) {
    const float* tok    = (const float*)d_in[0];
    const int*   wmask  = (const int*)d_in[1];
    const float* labe   = (const float*)d_in[3];
    const float* W_tok  = (const float*)d_in[4];
    const float* b_tok  = (const float*)d_in[5];
    const float* W_lab  = (const float*)d_in[6];
    const float* b_lab  = (const float*)d_in[7];
    const float* W1     = (const float*)d_in[8];
    const float* b1     = (const float*)d_in[9];
    const float* W2     = (const float*)d_in[10];
    const float* b2     = (const float*)d_in[11];
    float* out = (float*)d_out;

    const int L  = in_sizes[1];
    const int Wd = out_size / (Cn * 3);   // 1024

    char* ws = (char*)d_ws;
    size_t off = 0;
    auto alloc = [&](size_t bytes) { char* p = ws + off; off += (bytes + 255) & ~(size_t)255; return p; };
    // ---- persistent region ----
    int*   widx  = (int*)alloc(4096);
    float* Abuf  = (float*)alloc((size_t)Wd * Hd * 4);
    float* Bbuf  = (float*)alloc((size_t)Cn * Hd * 4);
    us* W1ct  = (us*)alloc((size_t)Hd * Hd * 2);   // fp16
    us* W1cl  = (us*)alloc((size_t)Hd * Hd * 2);   // unused
    us* t1b   = (us*)alloc((size_t)Wd * Hd * 2);   // fp16
    us* lb1b  = (us*)alloc((size_t)Cn * Hd * 2);   // fp16
    float* scr = (float*)alloc((size_t)6 * Wd * Cn * 3 * 4);   // 4.72 MB partials
    // ---- scratch region ----
    us* WtTh  = (us*)alloc((size_t)H2 * Hd * 2);
    us* WtTl  = (us*)alloc((size_t)H2 * Hd * 2);
    us* WlTh  = (us*)alloc((size_t)H2 * Hd * 2);
    us* WlTl  = (us*)alloc((size_t)H2 * Hd * 2);
    us* W1aTh = (us*)alloc((size_t)Hd * Hd * 2);
    us* W1aTl = (us*)alloc((size_t)Hd * Hd * 2);
    us* W1bTh = (us*)alloc((size_t)Hd * Hd * 2);
    us* W1bTl = (us*)alloc((size_t)Hd * Hd * 2);
    us* weh   = (us*)alloc((size_t)Wd * Hd * 2);
    us* wel   = (us*)alloc((size_t)Wd * Hd * 2);
    us* lah   = (us*)alloc((size_t)Cn * Hd * 2);
    us* lal   = (us*)alloc((size_t)Cn * Hd * 2);
    us* t0h   = (us*)alloc((size_t)Wd * Hd * 2);
    us* t0l   = (us*)alloc((size_t)Wd * Hd * 2);
    us* lb0h  = (us*)alloc((size_t)Cn * Hd * 2);
    us* lb0l  = (us*)alloc((size_t)Cn * Hd * 2);
    float* part = (float*)alloc((size_t)8 * Cn * H2 * 4);

    // 1) widx = -1 (kernel) + scatter + merged we/labe split
    k_init<<<(Wd + 255) / 256, 256, 0, stream>>>(widx, Wd);
    k_scatter<<<(L + 255) / 256, 256, 0, stream>>>(wmask, widx, L, Wd);
    k_build_we_labe<<<(Wd * 192 + Cn * 192 + 255) / 256, 256, 0, stream>>>(
        (const float4*)tok, widx, weh, wel, Wd, (const float4*)labe, lah, lal);

    // 2) batched weight transpose+split (W1c -> fp16)
    TSArgs ts;
    ts.src[0] = W_tok;  ts.th[0] = WtTh;  ts.tl[0] = WtTl;  ts.ld[0] = H2; ts.N[0] = H2; ts.fmt[0] = 0;
    ts.src[1] = W_lab;  ts.th[1] = WlTh;  ts.tl[1] = WlTl;  ts.ld[1] = H2; ts.N[1] = H2; ts.fmt[1] = 0;
    ts.src[2] = W1;                         ts.th[2] = W1aTh; ts.tl[2] = W1aTl; ts.ld[2] = Hd; ts.N[2] = Hd; ts.fmt[2] = 0;
    ts.src[3] = W1 + (size_t)Hd * Hd;       ts.th[3] = W1bTh; ts.tl[3] = W1bTl; ts.ld[3] = Hd; ts.N[3] = Hd; ts.fmt[3] = 0;
    ts.src[4] = W1 + (size_t)2 * Hd * Hd;   ts.th[4] = W1ct;  ts.tl[4] = W1cl;  ts.ld[4] = Hd; ts.N[4] = Hd; ts.fmt[4] = 1;
    k_tsplit<<<dim3(H2 / 64, Hd / 64, 5), 256, 0, stream>>>(ts);

    // 3) t = we @ W_tok + b_tok -> fused t0 hi/lo + t1b fp16
    k_gemm3<<<dim3(H2 / 64, Wd / 64), 256, 0, stream>>>(weh, wel, WtTh, WtTl, b_tok,
                                                        nullptr, t0h, t0l, t1b, 1, Hd, H2, Hd);

    // 4) lb = labe @ W_lab + b_lab (64x1536), z=8 K-split -> reduce (lb0 split + lb1b fp16)
    k_gemm2<<<dim3(H2 / 64, 1, 8), 256, 0, stream>>>(lah, lal, WlTh, WlTl, part, Cn, H2, Hd);
    k_reduce<<<(Cn * H2 + 255) / 256, 256, 0, stream>>>(part, 8, Cn * H2, H2, b_lab, nullptr, lb0h, lb0l, Hd, lb1b, 1);

    // 5) Aw = t0 @ W1a (1024x768) -> fused f32 write
    k_gemm3<<<dim3(Hd / 64, Wd / 64), 256, 0, stream>>>(t0h, t0l, W1aTh, W1aTl, nullptr,
                                                        Abuf, nullptr, nullptr, nullptr, 0, 0, Hd, Hd);

    // 6) Bc = lb0 @ W1b + b1 (64x768), z=8 K-split -> reduce
    k_gemm2<<<dim3(Hd / 64, 1, 8), 256, 0, stream>>>(lb0h, lb0l, W1bTh, W1bTl, part, Cn, Hd, Hd);
    k_reduce<<<(Cn * Hd + 255) / 256, 256, 0, stream>>>(part, 8, Cn * Hd, Hd, b1, Bbuf, nullptr, nullptr, Hd, nullptr, 0);

    // 7) fused fp16 P-GEMM v10 (session-final structure) -> scratch
    k_mfma10<<<1536, 256, 0, stream>>>(t1b, W1ct, lb1b, Abuf, Bbuf, W2, scr);

    // 8) out = b2 + sum_jx scr
    k_scores<<<(Wd * Cn * 3 + 255) / 256, 256, 0, stream>>>(scr, b2, out, Wd * Cn * 3);
}